// Round 6
// baseline (1044.697 us; speedup 1.0000x reference)
//
#include <hip/hip_runtime.h>
#include <hip/hip_bf16.h>

#define NN 100000
#define NE 1600000
#define NF 128
#define NH 64
#define NC 16
#define NB1 391    // ceil(NN/256)
#define GBIN 256   // binning workgroups
#define CHUNK 6250 // NE/GBIN
#define BBUK 196   // ceil(NN/512) coarse buckets of 512 nodes
#define NCB 196    // 256-blocks per counts array (BBUK*GBIN/256)
#define NGRP 1563  // ceil(NN/64) gemm1 row-groups

typedef __attribute__((ext_vector_type(8))) short short8v;
typedef __attribute__((ext_vector_type(4))) float float4v;

__device__ __forceinline__ float us2f(unsigned short u) {
    return __uint_as_float(((unsigned int)u) << 16);
}
__device__ __forceinline__ float bflo(unsigned u) {   // low bf16 of a packed pair
    return __uint_as_float(u << 16);
}
__device__ __forceinline__ float bfhi(unsigned u) {   // high bf16 of a packed pair
    return __uint_as_float(u & 0xFFFF0000u);
}
__device__ __forceinline__ unsigned short f2us_rn(float f) {
    unsigned int u = __float_as_uint(f);
    return (unsigned short)((u + 0x7FFFu + ((u >> 16) & 1u)) >> 16);
}
__device__ __forceinline__ float ldf(const void* p, size_t i, bool f32) {
    return f32 ? ((const float*)p)[i] : us2f(((const unsigned short*)p)[i]);
}

// ---------------- dtype sniff (validated R2; live mode=1/fp32 per R9) ----------------
__global__ void k_sniff(const unsigned short* __restrict__ xu, int* __restrict__ mode) {
    __shared__ int cnt;
    if (threadIdx.x == 0) cnt = 0;
    __syncthreads();
    int c = 0;
    for (int i = threadIdx.x; i < 4096; i += 256) {
        unsigned int e = (xu[i] >> 7) & 0xFFu;
        if (e >= 160u) c++;
    }
    atomicAdd(&cnt, c);
    __syncthreads();
    if (threadIdx.x == 0) mode[0] = (cnt >= 16) ? 1 : 0;
}

// ---------------- fallback path kernels (global atomics) ----------------
__global__ void k_deg(const int4* __restrict__ src4, const int4* __restrict__ dst4,
                      int* __restrict__ deg_out, int* __restrict__ deg_in) {
    int i = blockIdx.x * blockDim.x + threadIdx.x;
    if (i < NE / 4) {
        int4 s = src4[i], d = dst4[i];
        atomicAdd(&deg_out[s.x], 1); atomicAdd(&deg_out[s.y], 1);
        atomicAdd(&deg_out[s.z], 1); atomicAdd(&deg_out[s.w], 1);
        atomicAdd(&deg_in[d.x], 1);  atomicAdd(&deg_in[d.y], 1);
        atomicAdd(&deg_in[d.z], 1);  atomicAdd(&deg_in[d.w], 1);
    }
}

__global__ void k_scatter(const int* __restrict__ src, const int* __restrict__ dst,
                          int* __restrict__ cursor, int* __restrict__ srcs_sorted) {
    int e = blockIdx.x * blockDim.x + threadIdx.x;
    if (e < NE) {
        int p = atomicAdd(&cursor[dst[e]], 1);
        srcs_sorted[p] = src[e];
    }
}

__global__ void k_scan_a(const int* __restrict__ deg_in, int* __restrict__ bsum) {
    __shared__ int s[256];
    int i = blockIdx.x * 256 + threadIdx.x;
    s[threadIdx.x] = (i < NN) ? deg_in[i] : 0;
    __syncthreads();
    for (int off = 128; off > 0; off >>= 1) {
        if (threadIdx.x < off) s[threadIdx.x] += s[threadIdx.x + off];
        __syncthreads();
    }
    if (threadIdx.x == 0) bsum[blockIdx.x] = s[0];
}

__global__ void k_scan_b(const int* __restrict__ bsum, int* __restrict__ boff) {
    __shared__ int s[512];
    int t = threadIdx.x;
    s[t] = (t < NB1) ? bsum[t] : 0;
    __syncthreads();
    for (int off = 1; off < 512; off <<= 1) {
        int v = (t >= off) ? s[t - off] : 0;
        __syncthreads();
        s[t] += v;
        __syncthreads();
    }
    if (t < NB1) boff[t] = (t == 0) ? 0 : s[t - 1];
}

__global__ void k_scan_c(const int* __restrict__ deg_in, const int* __restrict__ deg_out,
                         const int* __restrict__ boff, int* __restrict__ row_off,
                         int* __restrict__ cursor, float* __restrict__ nsrc,
                         float* __restrict__ ndst) {
    __shared__ int s[256];
    int t = threadIdx.x;
    int i = blockIdx.x * 256 + t;
    int d = (i < NN) ? deg_in[i] : 0;
    s[t] = d;
    __syncthreads();
    for (int off = 1; off < 256; off <<= 1) {
        int v = (t >= off) ? s[t - off] : 0;
        __syncthreads();
        s[t] += v;
        __syncthreads();
    }
    int excl = s[t] - d + boff[blockIdx.x];
    if (i < NN) {
        row_off[i] = excl;
        cursor[i]  = excl;
        ndst[i] = rsqrtf(fmaxf((float)d, 1.0f));
        nsrc[i] = rsqrtf(fmaxf((float)deg_out[i], 1.0f));
        if (i == NN - 1) row_off[NN] = excl + d;
    }
}

// ---------------- fast CSR 1: per-(bucket,group) histograms of dst AND src ----------------
__global__ __launch_bounds__(256) void k_hist2(const int* __restrict__ src,
                                               const int* __restrict__ dst,
                                               int* __restrict__ counts_d,
                                               int* __restrict__ counts_s) {
    __shared__ int hd[BBUK], hs[BBUK];
    for (int i = threadIdx.x; i < BBUK; i += 256) { hd[i] = 0; hs[i] = 0; }
    __syncthreads();
    const int g = blockIdx.x;
    const int e0 = g * CHUNK;
    for (int i = threadIdx.x; i < CHUNK; i += 256) {
        atomicAdd(&hd[dst[e0 + i] >> 9], 1);
        atomicAdd(&hs[src[e0 + i] >> 9], 1);
    }
    __syncthreads();
    for (int i = threadIdx.x; i < BBUK; i += 256) {
        counts_d[i * GBIN + g] = hd[i];
        counts_s[i * GBIN + g] = hs[i];
    }
}

// ---------------- fast CSR 2: fused exclusive scan of both counts arrays ----------------
__global__ void k_cs_a(const int* __restrict__ counts, int* __restrict__ csum) {
    __shared__ int s[256];
    int i = blockIdx.x * 256 + threadIdx.x;
    s[threadIdx.x] = counts[i];
    __syncthreads();
    for (int off = 128; off > 0; off >>= 1) {
        if (threadIdx.x < off) s[threadIdx.x] += s[threadIdx.x + off];
        __syncthreads();
    }
    if (threadIdx.x == 0) csum[blockIdx.x] = s[0];
}

__global__ void k_cs_b2(const int* __restrict__ csum, int* __restrict__ coff) {
    __shared__ int s[512];
    int t = threadIdx.x;
    int half = t >> 8, j = t & 255;
    s[t] = (j < NCB) ? csum[half * NCB + j] : 0;
    __syncthreads();
    for (int off = 1; off < 256; off <<= 1) {
        int v = (j >= off) ? s[t - off] : 0;
        __syncthreads();
        s[t] += v;
        __syncthreads();
    }
    if (j < NCB) coff[half * NCB + j] = (j == 0) ? 0 : s[t - 1];
}

__global__ void k_cs_c(int* __restrict__ counts, const int* __restrict__ coff) {
    __shared__ int s[256];
    int t = threadIdx.x;
    int i = blockIdx.x * 256 + t;
    int v = counts[i];
    s[t] = v;
    __syncthreads();
    for (int off = 1; off < 256; off <<= 1) {
        int u = (t >= off) ? s[t - off] : 0;
        __syncthreads();
        s[t] += u;
        __syncthreads();
    }
    counts[i] = s[t] - v + coff[blockIdx.x];
}

// ---------------- fast CSR 3: private-slice binning of dst-edges AND src-residues ----------------
__global__ __launch_bounds__(256) void k_binscatter2(const int* __restrict__ src,
                                                     const int* __restrict__ dst,
                                                     const int* __restrict__ counts_d,
                                                     const int* __restrict__ counts_s,
                                                     unsigned int* __restrict__ packed,
                                                     unsigned short* __restrict__ packed2) {
    __shared__ int curd[BBUK], curs[BBUK];
    const int g = blockIdx.x;
    for (int i = threadIdx.x; i < BBUK; i += 256) {
        curd[i] = counts_d[i * GBIN + g];
        curs[i] = counts_s[i * GBIN + g];
    }
    __syncthreads();
    const int e0 = g * CHUNK;
    for (int i = threadIdx.x; i < CHUNK; i += 256) {
        int s = src[e0 + i], d = dst[e0 + i];
        int pd = atomicAdd(&curd[d >> 9], 1);
        packed[pd] = ((unsigned)s << 9) | (unsigned)(d & 511);
        int ps = atomicAdd(&curs[s >> 9], 1);
        packed2[ps] = (unsigned short)(s & 511);
    }
}

// ---------------- fast CSR 4: per-bucket out-degree histogram -> nsrc directly ----------------
__global__ __launch_bounds__(256) void k_bdeg_out_nsrc(const int* __restrict__ counts_s,
                                                       const unsigned short* __restrict__ packed2,
                                                       float* __restrict__ nsrc) {
    __shared__ int h[512];
    const int b = blockIdx.x;
    const int n0 = b << 9;
    const int nlim = (NN - n0 < 512) ? (NN - n0) : 512;
    for (int j = threadIdx.x; j < 512; j += 256) h[j] = 0;
    __syncthreads();
    const int beg = counts_s[b * GBIN];
    const int end = (b + 1 < BBUK) ? counts_s[(b + 1) * GBIN] : NE;
    for (int i = beg + threadIdx.x; i < end; i += 256)
        atomicAdd(&h[packed2[i] & 511u], 1);
    __syncthreads();
    for (int j = threadIdx.x; j < nlim; j += 256)
        nsrc[n0 + j] = rsqrtf(fmaxf((float)h[j], 1.0f));
}

// ---------------- W1 -> bf16 fragment-ordered layout ----------------
__global__ void k_prepW(const void* __restrict__ W1, unsigned short* __restrict__ W1f,
                        const int* __restrict__ mode) {
    const bool f32 = (mode[0] != 0);
    for (int i = threadIdx.x; i < 1024; i += 256) {
        const int kcnt = i >> 6, lane = i & 63;
        const int kc = kcnt >> 2, nt = kcnt & 3;
        const int quad = lane >> 4, col = lane & 15;
        #pragma unroll
        for (int j = 0; j < 8; ++j) {
            const size_t idx = (size_t)(kc * 32 + quad * 8 + j) * NH + nt * 16 + col;
            W1f[(size_t)i * 8 + j] = f32 ? f2us_rn(((const float*)W1)[idx])
                                         : ((const unsigned short*)W1)[idx];
        }
    }
}

// ---------------- layer 1 GEMM (MFMA, both dtypes) ----------------
__global__ __launch_bounds__(256) void k_gemm1_mfma(
    const void* __restrict__ x, const unsigned short* __restrict__ W1f,
    const float* __restrict__ nsrc, unsigned short* __restrict__ h1,
    const int* __restrict__ mode)
{
    const bool f32 = (mode[0] != 0);
    const int tid = threadIdx.x;
    const int wave = tid >> 6, lane = tid & 63;
    const int col = lane & 15, quad = lane >> 4;

    short8v bfrag[16];
    #pragma unroll
    for (int f = 0; f < 16; ++f)
        bfrag[f] = *(const short8v*)(W1f + ((size_t)f * 64 + lane) * 8);

    const int base = blockIdx.x * 64 + wave * 16;
    int arow = base + col;
    if (arow > NN - 1) arow = NN - 1;

    short8v afrag[4];
    if (f32) {
        const float4* ap = (const float4*)((const float*)x + (size_t)arow * NF);
        #pragma unroll
        for (int kc = 0; kc < 4; ++kc) {
            float4 v0 = ap[kc * 8 + quad * 2];
            float4 v1 = ap[kc * 8 + quad * 2 + 1];
            short8v af;
            af[0] = (short)f2us_rn(v0.x); af[1] = (short)f2us_rn(v0.y);
            af[2] = (short)f2us_rn(v0.z); af[3] = (short)f2us_rn(v0.w);
            af[4] = (short)f2us_rn(v1.x); af[5] = (short)f2us_rn(v1.y);
            af[6] = (short)f2us_rn(v1.z); af[7] = (short)f2us_rn(v1.w);
            afrag[kc] = af;
        }
    } else {
        const uint4* ap = (const uint4*)((const unsigned short*)x + (size_t)arow * NF);
        #pragma unroll
        for (int kc = 0; kc < 4; ++kc) {
            uint4 v = ap[kc * 4 + quad];
            afrag[kc] = *reinterpret_cast<const short8v*>(&v);
        }
    }

    float4v acc[4];
    #pragma unroll
    for (int nt = 0; nt < 4; ++nt) acc[nt] = (float4v){0.f, 0.f, 0.f, 0.f};
    #pragma unroll
    for (int kc = 0; kc < 4; ++kc)
        #pragma unroll
        for (int nt = 0; nt < 4; ++nt)
            acc[nt] = __builtin_amdgcn_mfma_f32_16x16x32_bf16(afrag[kc], bfrag[kc * 4 + nt], acc[nt], 0, 0, 0);

    #pragma unroll
    for (int reg = 0; reg < 4; ++reg) {
        const int row = base + quad * 4 + reg;
        if (row < NN) {
            const float ns = nsrc[row];
            unsigned short* hp = h1 + (size_t)row * NH + col;
            hp[0]  = f2us_rn(acc[0][reg] * ns);
            hp[16] = f2us_rn(acc[1][reg] * ns);
            hp[32] = f2us_rn(acc[2][reg] * ns);
            hp[48] = f2us_rn(acc[3][reg] * ns);
        }
    }
}

// ---------------- R17: bucket-LDS layer-1 aggregation + relu + W2 ----------------
// Replaces k_bucket_all + k_agg1csr in the fast path. Block = one HALF-bucket
// (256 nodes); scans the parent bucket's packed slice filtering on bit 8 of
// the dst residue. 16 lanes per edge gather h1[src] (uint2 each = 4 feats) and
// ds_add_f32 into acc[dstres&255][feat]. +65 pad -> atomics and epilogue reads
// are <=2-way bank aliased (free, m136). 72KB LDS -> 2 blocks/CU = 32 waves/CU.
// Epilogue: ndst=rsqrt(cnt), bias+relu+W2 (W2/b1 preloaded in LDS), h2 write.
__global__ __launch_bounds__(1024, 8) void k_aggbucket(
    const int* __restrict__ counts_d, const unsigned int* __restrict__ packed,
    const unsigned short* __restrict__ h1, const float* __restrict__ nsrc,
    const void* __restrict__ b1, const void* __restrict__ W2,
    const int* __restrict__ mode,
    float* __restrict__ ndst, unsigned short* __restrict__ h2)
{
    __shared__ float acc[256][65];
    __shared__ int   cnt[256];
    __shared__ float w2l[1024];
    __shared__ float b1l[64];

    const int t = threadIdx.x;
    const bool f32m = (mode[0] != 0);

    // zero accumulators + preload W2/b1
    float* af = &acc[0][0];
    for (int j = t; j < 256 * 65; j += 1024) af[j] = 0.f;
    if (t < 256) cnt[t] = 0;
    w2l[t] = ldf(W2, t, f32m);
    if (t < 64) b1l[t] = ldf(b1, t, f32m);
    __syncthreads();

    const int b    = blockIdx.x >> 1;     // parent 512-node bucket
    const int half = blockIdx.x & 1;      // which 256-node half
    const int beg = counts_d[b * GBIN];
    const int end = (b + 1 < BBUK) ? counts_d[(b + 1) * GBIN] : NE;

    const int g  = t >> 4;                // edge group 0..63
    const int li = t & 15;                // feature quad
    const uint2* __restrict__ h1v = (const uint2*)h1;
    const int e1 = end - 1;

    // 2-deep unrolled edge loop: both gathers in flight before consuming.
    for (int i = beg + g; i < end; i += 128) {
        const int ib = i + 64;
        const unsigned wa = packed[(unsigned)i];
        const unsigned wb = packed[(unsigned)((ib <= e1) ? ib : e1)];
        const bool ma = (((wa >> 8) & 1u) == (unsigned)half);
        const bool mb = (ib <= e1) && (((wb >> 8) & 1u) == (unsigned)half);
        uint2 va, vb;
        int dla = 0, dlb = 0;
        if (ma) {
            dla = (int)(wa & 255u);
            va = h1v[(wa >> 9) * 16u + (unsigned)li];
        }
        if (mb) {
            dlb = (int)(wb & 255u);
            vb = h1v[(wb >> 9) * 16u + (unsigned)li];
        }
        if (ma) {
            atomicAdd(&acc[dla][4 * li + 0], bflo(va.x));
            atomicAdd(&acc[dla][4 * li + 1], bfhi(va.x));
            atomicAdd(&acc[dla][4 * li + 2], bflo(va.y));
            atomicAdd(&acc[dla][4 * li + 3], bfhi(va.y));
            if (li == 0) atomicAdd(&cnt[dla], 1);
        }
        if (mb) {
            atomicAdd(&acc[dlb][4 * li + 0], bflo(vb.x));
            atomicAdd(&acc[dlb][4 * li + 1], bfhi(vb.x));
            atomicAdd(&acc[dlb][4 * li + 2], bflo(vb.y));
            atomicAdd(&acc[dlb][4 * li + 3], bfhi(vb.y));
            if (li == 0) atomicAdd(&cnt[dlb], 1);
        }
    }
    __syncthreads();

    // epilogue: 2 threads per node, 8 output classes each
    if (t < 512) {
        const int nl = t >> 1;            // node-local 0..255
        const int ch = t & 1;             // class half
        const int node = (b << 9) + (half << 8) + nl;
        if (node < NN) {
            const int deg = cnt[nl];
            const float nd = rsqrtf(fmaxf((float)deg, 1.0f));
            if (ch == 0) ndst[node] = nd;
            const float ns = nsrc[node];
            float p0 = 0.f, p1 = 0.f, p2 = 0.f, p3 = 0.f;
            float p4 = 0.f, p5 = 0.f, p6 = 0.f, p7 = 0.f;
            const int cb = ch * 8;
            #pragma unroll 8
            for (int f = 0; f < 64; ++f) {
                const float tf = fmaxf(fmaf(acc[nl][f], nd, b1l[f]), 0.f);
                const float* wr = &w2l[f * 16 + cb];
                p0 = fmaf(tf, wr[0], p0); p1 = fmaf(tf, wr[1], p1);
                p2 = fmaf(tf, wr[2], p2); p3 = fmaf(tf, wr[3], p3);
                p4 = fmaf(tf, wr[4], p4); p5 = fmaf(tf, wr[5], p5);
                p6 = fmaf(tf, wr[6], p6); p7 = fmaf(tf, wr[7], p7);
            }
            unsigned short* hp = h2 + (size_t)node * NC + cb;
            hp[0] = f2us_rn(p0 * ns); hp[1] = f2us_rn(p1 * ns);
            hp[2] = f2us_rn(p2 * ns); hp[3] = f2us_rn(p3 * ns);
            hp[4] = f2us_rn(p4 * ns); hp[5] = f2us_rn(p5 * ns);
            hp[6] = f2us_rn(p6 * ns); hp[7] = f2us_rn(p7 * ns);
        }
    }
}

// ---------------- R17: bucket-LDS layer-2 aggregation + bias + log_softmax ----------------
__global__ __launch_bounds__(1024, 8) void k_outbucket(
    const int* __restrict__ counts_d, const unsigned int* __restrict__ packed,
    const unsigned short* __restrict__ h2, const float* __restrict__ ndst,
    const void* __restrict__ b2, const int* __restrict__ mode,
    void* __restrict__ out)
{
    __shared__ float acc2[256][17];
    __shared__ float b2l[16];

    const int t = threadIdx.x;
    const bool f32m = (mode[0] != 0);

    float* af = &acc2[0][0];
    for (int j = t; j < 256 * 17; j += 1024) af[j] = 0.f;
    if (t < 16) b2l[t] = ldf(b2, t, f32m);
    __syncthreads();

    const int b    = blockIdx.x >> 1;
    const int half = blockIdx.x & 1;
    const int beg = counts_d[b * GBIN];
    const int end = (b + 1 < BBUK) ? counts_d[(b + 1) * GBIN] : NE;

    const int g   = t >> 3;               // edge group 0..127
    const int li2 = t & 7;                // class pair index
    const unsigned* __restrict__ h2v = (const unsigned*)h2;
    const int e1 = end - 1;

    for (int i = beg + g; i < end; i += 256) {
        const int ib = i + 128;
        const unsigned wa = packed[(unsigned)i];
        const unsigned wb = packed[(unsigned)((ib <= e1) ? ib : e1)];
        const bool ma = (((wa >> 8) & 1u) == (unsigned)half);
        const bool mb = (ib <= e1) && (((wb >> 8) & 1u) == (unsigned)half);
        unsigned ua, ub;
        int dla = 0, dlb = 0;
        if (ma) {
            dla = (int)(wa & 255u);
            ua = h2v[(wa >> 9) * 8u + (unsigned)li2];
        }
        if (mb) {
            dlb = (int)(wb & 255u);
            ub = h2v[(wb >> 9) * 8u + (unsigned)li2];
        }
        if (ma) {
            atomicAdd(&acc2[dla][2 * li2 + 0], bflo(ua));
            atomicAdd(&acc2[dla][2 * li2 + 1], bfhi(ua));
        }
        if (mb) {
            atomicAdd(&acc2[dlb][2 * li2 + 0], bflo(ub));
            atomicAdd(&acc2[dlb][2 * li2 + 1], bfhi(ub));
        }
    }
    __syncthreads();

    if (t < 256) {
        const int node = (b << 9) + (half << 8) + t;
        if (node < NN) {
            const float nd = ndst[node];
            // pass 1: max
            float m = -3.4e38f;
            #pragma unroll
            for (int c = 0; c < 16; ++c)
                m = fmaxf(m, fmaf(acc2[t][c], nd, b2l[c]));
            // pass 2: sum of exp
            float sm = 0.f;
            #pragma unroll
            for (int c = 0; c < 16; ++c)
                sm += __expf(fmaf(acc2[t][c], nd, b2l[c]) - m);
            const float lsm = __logf(sm);
            // pass 3: write
            if (f32m) {
                float* op = (float*)out + (size_t)node * NC;
                #pragma unroll
                for (int c = 0; c < 16; c += 2) {
                    float2 o;
                    o.x = fmaf(acc2[t][c + 0], nd, b2l[c + 0]) - m - lsm;
                    o.y = fmaf(acc2[t][c + 1], nd, b2l[c + 1]) - m - lsm;
                    *(float2*)(op + c) = o;
                }
            } else {
                unsigned short* op = (unsigned short*)out + (size_t)node * NC;
                #pragma unroll
                for (int c = 0; c < 16; c += 2) {
                    const float r0 = fmaf(acc2[t][c + 0], nd, b2l[c + 0]) - m - lsm;
                    const float r1 = fmaf(acc2[t][c + 1], nd, b2l[c + 1]) - m - lsm;
                    *(unsigned*)(op + c) =
                        ((unsigned)f2us_rn(r1) << 16) | (unsigned)f2us_rn(r0);
                }
            }
        }
    }
}

// ---------------- fallback-only: fused layer-1 aggregation (R12 form) ----------------
__global__ __launch_bounds__(256) void k_agg1csr(
    const int* __restrict__ row_off, const int* __restrict__ srcs,
    const unsigned short* __restrict__ h1, const float* __restrict__ ndst,
    const float* __restrict__ nsrc, const void* __restrict__ b1,
    const void* __restrict__ W2, const int* __restrict__ mode,
    unsigned short* __restrict__ h2)
{
    const bool f32 = (mode[0] != 0);
    const int lane = threadIdx.x & 63;
    const int q  = lane >> 4;
    const int li = lane & 15;

    const float bias0 = ldf(b1, 4*li+0, f32), bias1 = ldf(b1, 4*li+1, f32);
    const float bias2 = ldf(b1, 4*li+2, f32), bias3 = ldf(b1, 4*li+3, f32);
    float w2[4][4];
    #pragma unroll
    for (int j = 0; j < 4; ++j)
        #pragma unroll
        for (int m = 0; m < 4; ++m)
            w2[j][m] = ldf(W2, (size_t)(4*li+j)*NC + (q + 4*m), f32);

    const int wid = (blockIdx.x * blockDim.x + threadIdx.x) >> 6;
    const int nw  = (gridDim.x * blockDim.x) >> 6;
    const uint2* __restrict__ h1v = (const uint2*)h1;
    const unsigned uli = (unsigned)li;

    int row = wid;
    if (row >= NN) return;
    int beg = row_off[row];
    int end = row_off[row + 1];
    float nd = ndst[row];
    float ns = nsrc[row];

    while (row < NN) {
        const int nrow = row + nw;
        int nbeg = 0, nend = 0;
        float nnd = 0.f, nns = 0.f;
        if (nrow < NN) {
            nbeg = row_off[nrow];
            nend = row_off[nrow + 1];
            nnd  = ndst[nrow];
            nns  = nsrc[nrow];
        }

        float ax = 0.f, ay = 0.f, az = 0.f, aw = 0.f;
        float bx = 0.f, by = 0.f, bz = 0.f, bw = 0.f;
        const int e1 = end - 1;
        int i = beg + q;
        while (i < end) {
            const int j1 = i + 4, j2 = i + 8, j3 = i + 12;
            const int t1 = (j1 < end) ? j1 : e1;
            const int t2 = (j2 < end) ? j2 : e1;
            const int t3 = (j3 < end) ? j3 : e1;
            const int s0 = srcs[(unsigned)i];
            const int s1 = srcs[(unsigned)t1];
            const int s2 = srcs[(unsigned)t2];
            const int s3 = srcs[(unsigned)t3];
            const uint2 v0 = h1v[(unsigned)s0 * 16u + uli];
            const uint2 v1 = h1v[(unsigned)s1 * 16u + uli];
            const uint2 v2 = h1v[(unsigned)s2 * 16u + uli];
            const uint2 v3 = h1v[(unsigned)s3 * 16u + uli];
            ax += bflo(v0.x); ay += bfhi(v0.x);
            az += bflo(v0.y); aw += bfhi(v0.y);
            if (j1 < end) {
                bx += bflo(v1.x); by += bfhi(v1.x);
                bz += bflo(v1.y); bw += bfhi(v1.y);
            }
            if (j2 < end) {
                ax += bflo(v2.x); ay += bfhi(v2.x);
                az += bflo(v2.y); aw += bfhi(v2.y);
            }
            if (j3 < end) {
                bx += bflo(v3.x); by += bfhi(v3.x);
                bz += bflo(v3.y); bw += bfhi(v3.y);
            }
            i += 16;
        }
        ax += bx; ay += by; az += bz; aw += bw;
        ax += __shfl_xor(ax, 16); ay += __shfl_xor(ay, 16);
        az += __shfl_xor(az, 16); aw += __shfl_xor(aw, 16);
        ax += __shfl_xor(ax, 32); ay += __shfl_xor(ay, 32);
        az += __shfl_xor(az, 32); aw += __shfl_xor(aw, 32);

        const float t0 = fmaxf(fmaf(ax, nd, bias0), 0.f);
        const float t1f = fmaxf(fmaf(ay, nd, bias1), 0.f);
        const float t2f = fmaxf(fmaf(az, nd, bias2), 0.f);
        const float t3f = fmaxf(fmaf(aw, nd, bias3), 0.f);

        float p0 = fmaf(t0,w2[0][0],fmaf(t1f,w2[1][0],fmaf(t2f,w2[2][0],t3f*w2[3][0])));
        float p1 = fmaf(t0,w2[0][1],fmaf(t1f,w2[1][1],fmaf(t2f,w2[2][1],t3f*w2[3][1])));
        float p2 = fmaf(t0,w2[0][2],fmaf(t1f,w2[1][2],fmaf(t2f,w2[2][2],t3f*w2[3][2])));
        float p3 = fmaf(t0,w2[0][3],fmaf(t1f,w2[1][3],fmaf(t2f,w2[2][3],t3f*w2[3][3])));
        #pragma unroll
        for (int off = 1; off <= 8; off <<= 1) {
            p0 += __shfl_xor(p0, off);
            p1 += __shfl_xor(p1, off);
            p2 += __shfl_xor(p2, off);
            p3 += __shfl_xor(p3, off);
        }
        if (li < 4) {
            float v = (li == 0) ? p0 : (li == 1) ? p1 : (li == 2) ? p2 : p3;
            h2[(size_t)row * NC + q + 4*li] = f2us_rn(v * ns);
        }

        row = nrow; beg = nbeg; end = nend; nd = nnd; ns = nns;
    }
}

// ---------------- fallback-only: fused layer-2 aggregation + log_softmax ----------------
__global__ __launch_bounds__(256) void k_out(
    const int* __restrict__ row_off, const int* __restrict__ srcs,
    const unsigned short* __restrict__ h2, const float* __restrict__ ndst,
    const void* __restrict__ b2, const int* __restrict__ mode,
    void* __restrict__ out)
{
    const bool f32 = (mode[0] != 0);
    const int lane = threadIdx.x & 63;
    const int q  = lane >> 3;
    const int li = lane & 7;
    const float b2v0 = ldf(b2, 2*li,   f32);
    const float b2v1 = ldf(b2, 2*li+1, f32);

    const int wid = (blockIdx.x * blockDim.x + threadIdx.x) >> 6;
    const int nw  = (gridDim.x * blockDim.x) >> 6;
    const unsigned* __restrict__ h2v = (const unsigned*)h2;
    const unsigned uli = (unsigned)li;

    int row = wid;
    if (row >= NN) return;
    int beg = row_off[row];
    int end = row_off[row + 1];
    float nd = ndst[row];

    while (row < NN) {
        const int nrow = row + nw;
        int nbeg = 0, nend = 0;
        float nnd = 0.f;
        if (nrow < NN) {
            nbeg = row_off[nrow];
            nend = row_off[nrow + 1];
            nnd  = ndst[nrow];
        }

        float a0 = 0.f, a1 = 0.f, c0 = 0.f, c1 = 0.f;
        const int e1 = end - 1;
        int i = beg + q;
        while (i < end) {
            const int j1 = i + 8;
            const int t1 = (j1 < end) ? j1 : e1;
            const int s0 = srcs[(unsigned)i];
            const int s1 = srcs[(unsigned)t1];
            const unsigned u0 = h2v[(unsigned)s0 * 8u + uli];
            const unsigned u1 = h2v[(unsigned)s1 * 8u + uli];
            a0 += bflo(u0); a1 += bfhi(u0);
            if (j1 < end) {
                c0 += bflo(u1); c1 += bfhi(u1);
            }
            i += 16;
        }
        a0 += c0; a1 += c1;
        #pragma unroll
        for (int off = 8; off <= 32; off <<= 1) {
            a0 += __shfl_xor(a0, off);
            a1 += __shfl_xor(a1, off);
        }
        float v0 = fmaf(a0, nd, b2v0);
        float v1 = fmaf(a1, nd, b2v1);
        float m = fmaxf(v0, v1);
        #pragma unroll
        for (int off = 1; off <= 4; off <<= 1) m = fmaxf(m, __shfl_xor(m, off));
        float sm = __expf(v0 - m) + __expf(v1 - m);
        #pragma unroll
        for (int off = 1; off <= 4; off <<= 1) sm += __shfl_xor(sm, off);
        const float lsm = __logf(sm);
        const float r0 = v0 - m - lsm, r1 = v1 - m - lsm;
        if (q == 0) {
            if (f32) {
                float2 o; o.x = r0; o.y = r1;
                *(float2*)((float*)out + (size_t)row * NC + 2*li) = o;
            } else {
                unsigned o = ((unsigned)f2us_rn(r1) << 16) | (unsigned)f2us_rn(r0);
                *(unsigned*)((unsigned short*)out + (size_t)row * NC + 2*li) = o;
            }
        }

        row = nrow; beg = nbeg; end = nend; nd = nnd;
    }
}

extern "C" void kernel_launch(void* const* d_in, const int* in_sizes, int n_in,
                              void* d_out, int out_size, void* d_ws, size_t ws_size,
                              hipStream_t stream) {
    const void* x  = d_in[0];
    const int* src = (const int*)d_in[1];
    const int* dst = (const int*)d_in[2];
    const void* W1 = d_in[3];
    const void* b1 = d_in[4];
    const void* W2 = d_in[5];
    const void* b2 = d_in[6];

    // ---- workspace layout ----
    char* ws = (char*)d_ws;
    const size_t O_MODE = 0;                     // 1 KB
    const size_t O_W1F  = 1024;                  // fragment-ordered W1 (bf16), 16384 B
    const size_t O_CNT  = O_W1F + 16384;         // counts_d + counts_s = 401408
    const size_t O_CS   = O_CNT  + 401408;       // csum 2048 + coff 2048
    const size_t O_DEG  = O_CS   + 4096;         // 800000 (fallback only)
    const size_t O_NSRC = O_DEG  + 800000;
    const size_t O_NDST = O_NSRC + 400000;
    const size_t O_ROW  = O_NDST + 400000;       // (NN+1)*4 padded (fallback only)
    const size_t O_CUR  = O_ROW  + 400128;       // fallback per-node cursors
    const size_t O_BS   = O_CUR  + 400128;       // bsum 2048 + boff 2048 (fallback)
    const size_t O_SRCS = O_BS   + 4096;         // NE*4: fallback srcs_sorted; FAST: packed
    const size_t O_H2   = O_SRCS + 6400000;      // NN*NC*2 bf16
    const size_t O_H1   = O_H2   + 3200000;      // NN*NH*2 bf16 = 12800000
    // R17 lifetime fix: packed lives in O_SRCS (srcs_sorted unused in fast path)
    // so it SURVIVES gemm1's h1 write for k_outbucket. packed2 (NE*2) aliases
    // h1 (dead before gemm1).
    const size_t NEED = O_H1 + 12800000;         // ~25.2 MB (unchanged)
    const bool fast_csr = ws_size >= NEED;

    int*   mode     = (int*)(ws + O_MODE);
    unsigned short* W1f = (unsigned short*)(ws + O_W1F);
    int*   counts_d = (int*)(ws + O_CNT);
    int*   counts_s = counts_d + BBUK * GBIN;
    int*   csum     = (int*)(ws + O_CS);
    int*   coff     = (int*)(ws + O_CS + 2048);
    int*   deg_out  = (int*)(ws + O_DEG);
    int*   deg_in   = deg_out + NN;
    float* nsrc     = (float*)(ws + O_NSRC);
    float* ndst     = (float*)(ws + O_NDST);
    int*   row_off  = (int*)(ws + O_ROW);
    int*   cursor   = (int*)(ws + O_CUR);
    int*   bsum     = (int*)(ws + O_BS);
    int*   boff     = (int*)(ws + O_BS + 2048);
    int*   srcs_s   = (int*)(ws + O_SRCS);
    unsigned short* h2 = (unsigned short*)(ws + O_H2);
    unsigned short* h1 = (unsigned short*)(ws + O_H1);
    unsigned int*   packed  = (unsigned int*)(ws + O_SRCS);
    unsigned short* packed2 = (unsigned short*)(ws + O_H1);

    k_sniff<<<1, 256, 0, stream>>>((const unsigned short*)x, mode);
    k_prepW<<<1, 256, 0, stream>>>(W1, W1f, mode);
    if (fast_csr) {
        k_hist2<<<GBIN, 256, 0, stream>>>(src, dst, counts_d, counts_s);
        k_cs_a<<<2 * NCB, 256, 0, stream>>>(counts_d, csum);
        k_cs_b2<<<1, 512, 0, stream>>>(csum, coff);
        k_cs_c<<<2 * NCB, 256, 0, stream>>>(counts_d, coff);
        k_binscatter2<<<GBIN, 256, 0, stream>>>(src, dst, counts_d, counts_s, packed, packed2);
        k_bdeg_out_nsrc<<<BBUK, 256, 0, stream>>>(counts_s, packed2, nsrc);
        k_gemm1_mfma<<<NGRP, 256, 0, stream>>>(x, W1f, nsrc, h1, mode);
        k_aggbucket<<<2 * BBUK, 1024, 0, stream>>>(counts_d, packed, h1, nsrc, b1, W2, mode, ndst, h2);
        k_outbucket<<<2 * BBUK, 1024, 0, stream>>>(counts_d, packed, h2, ndst, b2, mode, d_out);
    } else {
        hipMemsetAsync(deg_out, 0, 2 * (size_t)NN * sizeof(int), stream);
        k_deg<<<(NE / 4 + 255) / 256, 256, 0, stream>>>((const int4*)src, (const int4*)dst, deg_out, deg_in);
        k_scan_a<<<NB1, 256, 0, stream>>>(deg_in, bsum);
        k_scan_b<<<1, 512, 0, stream>>>(bsum, boff);
        k_scan_c<<<NB1, 256, 0, stream>>>(deg_in, deg_out, boff, row_off, cursor, nsrc, ndst);
        k_scatter<<<(NE + 255) / 256, 256, 0, stream>>>(src, dst, cursor, srcs_s);
        k_gemm1_mfma<<<NGRP, 256, 0, stream>>>(x, W1f, nsrc, h1, mode);
        k_agg1csr<<<2048, 256, 0, stream>>>(row_off, srcs_s, h1, ndst, nsrc, b1, W2, mode, h2);
        k_out<<<2048, 256, 0, stream>>>(row_off, srcs_s, h2, ndst, b2, mode, d_out);
    }
}

// Round 7
// 275.679 us; speedup vs baseline: 3.7895x; 3.7895x over previous
//
#include <hip/hip_runtime.h>
#include <hip/hip_bf16.h>

#define NN 100000
#define NE 1600000
#define NF 128
#define NH 64
#define NC 16
#define NB1 391    // ceil(NN/256)
#define GBIN 256   // binning workgroups
#define CHUNK 6250 // NE/GBIN
#define BBUK 196   // ceil(NN/512) coarse buckets of 512 nodes
#define NCB 196    // 256-blocks per counts array (BBUK*GBIN/256)
#define NGRP 1563  // ceil(NN/64) gemm1 row-groups

typedef __attribute__((ext_vector_type(8))) short short8v;
typedef __attribute__((ext_vector_type(4))) float float4v;

__device__ __forceinline__ float us2f(unsigned short u) {
    return __uint_as_float(((unsigned int)u) << 16);
}
__device__ __forceinline__ float bflo(unsigned u) {   // low bf16 of a packed pair
    return __uint_as_float(u << 16);
}
__device__ __forceinline__ float bfhi(unsigned u) {   // high bf16 of a packed pair
    return __uint_as_float(u & 0xFFFF0000u);
}
__device__ __forceinline__ unsigned short f2us_rn(float f) {
    unsigned int u = __float_as_uint(f);
    return (unsigned short)((u + 0x7FFFu + ((u >> 16) & 1u)) >> 16);
}
__device__ __forceinline__ float ldf(const void* p, size_t i, bool f32) {
    return f32 ? ((const float*)p)[i] : us2f(((const unsigned short*)p)[i]);
}

// ---------------- R18: fused dtype sniff + W1 fragment repack (1 block) ----------------
__global__ void k_sniffprep(const unsigned short* __restrict__ xu,
                            const void* __restrict__ W1,
                            unsigned short* __restrict__ W1f,
                            int* __restrict__ mode) {
    __shared__ int cnt;
    if (threadIdx.x == 0) cnt = 0;
    __syncthreads();
    int c = 0;
    for (int i = threadIdx.x; i < 4096; i += 256) {
        unsigned int e = (xu[i] >> 7) & 0xFFu;
        if (e >= 160u) c++;
    }
    atomicAdd(&cnt, c);
    __syncthreads();
    if (threadIdx.x == 0) mode[0] = (cnt >= 16) ? 1 : 0;
    __syncthreads();
    const bool f32 = (cnt >= 16);
    for (int i = threadIdx.x; i < 1024; i += 256) {
        const int kcnt = i >> 6, lane = i & 63;
        const int kc = kcnt >> 2, nt = kcnt & 3;
        const int quad = lane >> 4, col = lane & 15;
        #pragma unroll
        for (int j = 0; j < 8; ++j) {
            const size_t idx = (size_t)(kc * 32 + quad * 8 + j) * NH + nt * 16 + col;
            W1f[(size_t)i * 8 + j] = f32 ? f2us_rn(((const float*)W1)[idx])
                                         : ((const unsigned short*)W1)[idx];
        }
    }
}

// ---------------- fallback path kernels (global atomics) ----------------
__global__ void k_deg(const int4* __restrict__ src4, const int4* __restrict__ dst4,
                      int* __restrict__ deg_out, int* __restrict__ deg_in) {
    int i = blockIdx.x * blockDim.x + threadIdx.x;
    if (i < NE / 4) {
        int4 s = src4[i], d = dst4[i];
        atomicAdd(&deg_out[s.x], 1); atomicAdd(&deg_out[s.y], 1);
        atomicAdd(&deg_out[s.z], 1); atomicAdd(&deg_out[s.w], 1);
        atomicAdd(&deg_in[d.x], 1);  atomicAdd(&deg_in[d.y], 1);
        atomicAdd(&deg_in[d.z], 1);  atomicAdd(&deg_in[d.w], 1);
    }
}

__global__ void k_scatter(const int* __restrict__ src, const int* __restrict__ dst,
                          int* __restrict__ cursor, int* __restrict__ srcs_sorted) {
    int e = blockIdx.x * blockDim.x + threadIdx.x;
    if (e < NE) {
        int p = atomicAdd(&cursor[dst[e]], 1);
        srcs_sorted[p] = src[e];
    }
}

__global__ void k_scan_a(const int* __restrict__ deg_in, int* __restrict__ bsum) {
    __shared__ int s[256];
    int i = blockIdx.x * 256 + threadIdx.x;
    s[threadIdx.x] = (i < NN) ? deg_in[i] : 0;
    __syncthreads();
    for (int off = 128; off > 0; off >>= 1) {
        if (threadIdx.x < off) s[threadIdx.x] += s[threadIdx.x + off];
        __syncthreads();
    }
    if (threadIdx.x == 0) bsum[blockIdx.x] = s[0];
}

__global__ void k_scan_b(const int* __restrict__ bsum, int* __restrict__ boff) {
    __shared__ int s[512];
    int t = threadIdx.x;
    s[t] = (t < NB1) ? bsum[t] : 0;
    __syncthreads();
    for (int off = 1; off < 512; off <<= 1) {
        int v = (t >= off) ? s[t - off] : 0;
        __syncthreads();
        s[t] += v;
        __syncthreads();
    }
    if (t < NB1) boff[t] = (t == 0) ? 0 : s[t - 1];
}

__global__ void k_scan_c(const int* __restrict__ deg_in, const int* __restrict__ deg_out,
                         const int* __restrict__ boff, int* __restrict__ row_off,
                         int* __restrict__ cursor, float* __restrict__ nsrc,
                         float* __restrict__ ndst) {
    __shared__ int s[256];
    int t = threadIdx.x;
    int i = blockIdx.x * 256 + t;
    int d = (i < NN) ? deg_in[i] : 0;
    s[t] = d;
    __syncthreads();
    for (int off = 1; off < 256; off <<= 1) {
        int v = (t >= off) ? s[t - off] : 0;
        __syncthreads();
        s[t] += v;
        __syncthreads();
    }
    int excl = s[t] - d + boff[blockIdx.x];
    if (i < NN) {
        row_off[i] = excl;
        cursor[i]  = excl;
        ndst[i] = rsqrtf(fmaxf((float)d, 1.0f));
        nsrc[i] = rsqrtf(fmaxf((float)deg_out[i], 1.0f));
        if (i == NN - 1) row_off[NN] = excl + d;
    }
}

// ---------------- fast CSR 1: per-(bucket,group) histograms of dst AND src ----------------
__global__ __launch_bounds__(256) void k_hist2(const int* __restrict__ src,
                                               const int* __restrict__ dst,
                                               int* __restrict__ counts_d,
                                               int* __restrict__ counts_s) {
    __shared__ int hd[BBUK], hs[BBUK];
    for (int i = threadIdx.x; i < BBUK; i += 256) { hd[i] = 0; hs[i] = 0; }
    __syncthreads();
    const int g = blockIdx.x;
    const int e0 = g * CHUNK;
    for (int i = threadIdx.x; i < CHUNK; i += 256) {
        atomicAdd(&hd[dst[e0 + i] >> 9], 1);
        atomicAdd(&hs[src[e0 + i] >> 9], 1);
    }
    __syncthreads();
    for (int i = threadIdx.x; i < BBUK; i += 256) {
        counts_d[i * GBIN + g] = hd[i];
        counts_s[i * GBIN + g] = hs[i];
    }
}

// ---------------- fast CSR 2: fused exclusive scan of both counts arrays ----------------
__global__ void k_cs_a(const int* __restrict__ counts, int* __restrict__ csum) {
    __shared__ int s[256];
    int i = blockIdx.x * 256 + threadIdx.x;
    s[threadIdx.x] = counts[i];
    __syncthreads();
    for (int off = 128; off > 0; off >>= 1) {
        if (threadIdx.x < off) s[threadIdx.x] += s[threadIdx.x + off];
        __syncthreads();
    }
    if (threadIdx.x == 0) csum[blockIdx.x] = s[0];
}

__global__ void k_cs_b2(const int* __restrict__ csum, int* __restrict__ coff) {
    __shared__ int s[512];
    int t = threadIdx.x;
    int half = t >> 8, j = t & 255;
    s[t] = (j < NCB) ? csum[half * NCB + j] : 0;
    __syncthreads();
    for (int off = 1; off < 256; off <<= 1) {
        int v = (j >= off) ? s[t - off] : 0;
        __syncthreads();
        s[t] += v;
        __syncthreads();
    }
    if (j < NCB) coff[half * NCB + j] = (j == 0) ? 0 : s[t - 1];
}

__global__ void k_cs_c(int* __restrict__ counts, const int* __restrict__ coff) {
    __shared__ int s[256];
    int t = threadIdx.x;
    int i = blockIdx.x * 256 + t;
    int v = counts[i];
    s[t] = v;
    __syncthreads();
    for (int off = 1; off < 256; off <<= 1) {
        int u = (t >= off) ? s[t - off] : 0;
        __syncthreads();
        s[t] += u;
        __syncthreads();
    }
    counts[i] = s[t] - v + coff[blockIdx.x];
}

// ---------------- fast CSR 3: private-slice binning of dst-edges AND src-residues ----------------
__global__ __launch_bounds__(256) void k_binscatter2(const int* __restrict__ src,
                                                     const int* __restrict__ dst,
                                                     const int* __restrict__ counts_d,
                                                     const int* __restrict__ counts_s,
                                                     unsigned int* __restrict__ packed,
                                                     unsigned short* __restrict__ packed2) {
    __shared__ int curd[BBUK], curs[BBUK];
    const int g = blockIdx.x;
    for (int i = threadIdx.x; i < BBUK; i += 256) {
        curd[i] = counts_d[i * GBIN + g];
        curs[i] = counts_s[i * GBIN + g];
    }
    __syncthreads();
    const int e0 = g * CHUNK;
    for (int i = threadIdx.x; i < CHUNK; i += 256) {
        int s = src[e0 + i], d = dst[e0 + i];
        int pd = atomicAdd(&curd[d >> 9], 1);
        packed[pd] = ((unsigned)s << 9) | (unsigned)(d & 511);
        int ps = atomicAdd(&curs[s >> 9], 1);
        packed2[ps] = (unsigned short)(s & 511);
    }
}

// ---------------- R18: fused fast CSR 4+5 (one kernel, 196 blocks) ----------------
// Phase 1 (was k_bdeg_out_nsrc): out-degree histogram over packed2 -> nsrc.
// Phase 2 (was k_bucket_all): in-deg histogram + Blelloch scan + row_off/ndst
// + within-bucket scatter to srcs_sorted. LDS h[512] reused across phases.
__global__ __launch_bounds__(256) void k_bucket2(const int* __restrict__ counts_d,
                                                 const int* __restrict__ counts_s,
                                                 const unsigned int* __restrict__ packed,
                                                 const unsigned short* __restrict__ packed2,
                                                 int* __restrict__ row_off,
                                                 float* __restrict__ ndst,
                                                 float* __restrict__ nsrc,
                                                 int* __restrict__ srcs_sorted) {
    __shared__ int h[512];
    const int b = blockIdx.x;
    const int n0 = b << 9;
    const int nlim = (NN - n0 < 512) ? (NN - n0) : 512;
    const int t = threadIdx.x;

    // ---- phase 1: src-side out-degree -> nsrc ----
    for (int j = t; j < 512; j += 256) h[j] = 0;
    __syncthreads();
    {
        const int sbeg = counts_s[b * GBIN];
        const int send = (b + 1 < BBUK) ? counts_s[(b + 1) * GBIN] : NE;
        for (int i = sbeg + t; i < send; i += 256)
            atomicAdd(&h[packed2[i] & 511u], 1);
    }
    __syncthreads();
    for (int j = t; j < nlim; j += 256)
        nsrc[n0 + j] = rsqrtf(fmaxf((float)h[j], 1.0f));
    __syncthreads();

    // ---- phase 2: dst-side CSR build ----
    for (int j = t; j < 512; j += 256) h[j] = 0;
    __syncthreads();
    const int beg = counts_d[b * GBIN];
    const int end = (b + 1 < BBUK) ? counts_d[(b + 1) * GBIN] : NE;
    // 1) in-degree histogram over this bucket's packed slice
    for (int i = beg + t; i < end; i += 256)
        atomicAdd(&h[packed[i] & 511u], 1);
    __syncthreads();
    const int degA = h[t], degB = h[t + 256];   // saved for ndst
    // 2) Blelloch exclusive scan of 512 elems (256 threads)
    int offset = 1;
    #pragma unroll
    for (int d = 256; d > 0; d >>= 1) {
        __syncthreads();
        if (t < d) {
            int ai = offset * (2 * t + 1) - 1;
            int bi = offset * (2 * t + 2) - 1;
            h[bi] += h[ai];
        }
        offset <<= 1;
    }
    __syncthreads();
    if (t == 0) h[511] = 0;
    #pragma unroll
    for (int d = 1; d < 512; d <<= 1) {
        offset >>= 1;
        __syncthreads();
        if (t < d) {
            int ai = offset * (2 * t + 1) - 1;
            int bi = offset * (2 * t + 2) - 1;
            int tmp = h[ai]; h[ai] = h[bi]; h[bi] += tmp;
        }
    }
    __syncthreads();
    // 3) row_off / ndst
    const int r0 = beg + h[t];
    const int r1 = beg + h[t + 256];
    if (t < nlim) {
        row_off[n0 + t] = r0;
        ndst[n0 + t] = rsqrtf(fmaxf((float)degA, 1.0f));
    }
    if (t + 256 < nlim) {
        row_off[n0 + t + 256] = r1;
        ndst[n0 + t + 256] = rsqrtf(fmaxf((float)degB, 1.0f));
    }
    if (n0 + nlim == NN && t == 0) row_off[NN] = end;
    __syncthreads();
    h[t] = r0; h[t + 256] = r1;   // LDS cursors
    __syncthreads();
    // 4) within-bucket scatter (re-read is L2-hot)
    for (int i = beg + t; i < end; i += 256) {
        unsigned v = packed[i];
        int p = atomicAdd(&h[v & 511u], 1);
        srcs_sorted[p] = (int)(v >> 9);
    }
}

// ---------------- layer 1 GEMM (MFMA, both dtypes) ----------------
__global__ __launch_bounds__(256) void k_gemm1_mfma(
    const void* __restrict__ x, const unsigned short* __restrict__ W1f,
    const float* __restrict__ nsrc, unsigned short* __restrict__ h1,
    const int* __restrict__ mode)
{
    const bool f32 = (mode[0] != 0);
    const int tid = threadIdx.x;
    const int wave = tid >> 6, lane = tid & 63;
    const int col = lane & 15, quad = lane >> 4;

    short8v bfrag[16];
    #pragma unroll
    for (int f = 0; f < 16; ++f)
        bfrag[f] = *(const short8v*)(W1f + ((size_t)f * 64 + lane) * 8);

    const int base = blockIdx.x * 64 + wave * 16;
    int arow = base + col;
    if (arow > NN - 1) arow = NN - 1;

    short8v afrag[4];
    if (f32) {
        const float4* ap = (const float4*)((const float*)x + (size_t)arow * NF);
        #pragma unroll
        for (int kc = 0; kc < 4; ++kc) {
            float4 v0 = ap[kc * 8 + quad * 2];
            float4 v1 = ap[kc * 8 + quad * 2 + 1];
            short8v af;
            af[0] = (short)f2us_rn(v0.x); af[1] = (short)f2us_rn(v0.y);
            af[2] = (short)f2us_rn(v0.z); af[3] = (short)f2us_rn(v0.w);
            af[4] = (short)f2us_rn(v1.x); af[5] = (short)f2us_rn(v1.y);
            af[6] = (short)f2us_rn(v1.z); af[7] = (short)f2us_rn(v1.w);
            afrag[kc] = af;
        }
    } else {
        const uint4* ap = (const uint4*)((const unsigned short*)x + (size_t)arow * NF);
        #pragma unroll
        for (int kc = 0; kc < 4; ++kc) {
            uint4 v = ap[kc * 4 + quad];
            afrag[kc] = *reinterpret_cast<const short8v*>(&v);
        }
    }

    float4v acc[4];
    #pragma unroll
    for (int nt = 0; nt < 4; ++nt) acc[nt] = (float4v){0.f, 0.f, 0.f, 0.f};
    #pragma unroll
    for (int kc = 0; kc < 4; ++kc)
        #pragma unroll
        for (int nt = 0; nt < 4; ++nt)
            acc[nt] = __builtin_amdgcn_mfma_f32_16x16x32_bf16(afrag[kc], bfrag[kc * 4 + nt], acc[nt], 0, 0, 0);

    #pragma unroll
    for (int reg = 0; reg < 4; ++reg) {
        const int row = base + quad * 4 + reg;
        if (row < NN) {
            const float ns = nsrc[row];
            unsigned short* hp = h1 + (size_t)row * NH + col;
            hp[0]  = f2us_rn(acc[0][reg] * ns);
            hp[16] = f2us_rn(acc[1][reg] * ns);
            hp[32] = f2us_rn(acc[2][reg] * ns);
            hp[48] = f2us_rn(acc[3][reg] * ns);
        }
    }
}

// ---------------- fused layer-1 aggregation + relu + W2 GEMM ----------------
// R12 body - FROZEN. History: R11 wider slots 70us, R13 two-row 71us, R14
// gload_lds prefetch 98us, R17 bucket-LDS 700us - all reverted. 60us = this
// gather structure's floor: 89MB L2-miss traffic (mostly L3-hit) at 1.46 TB/s,
// MSHR/concurrency bound; more per-wave MLP only lengthens in-order vmcnt
// drain chains.
__global__ __launch_bounds__(256) void k_agg1csr(
    const int* __restrict__ row_off, const int* __restrict__ srcs,
    const unsigned short* __restrict__ h1, const float* __restrict__ ndst,
    const float* __restrict__ nsrc, const void* __restrict__ b1,
    const void* __restrict__ W2, const int* __restrict__ mode,
    unsigned short* __restrict__ h2)
{
    const bool f32 = (mode[0] != 0);
    const int lane = threadIdx.x & 63;
    const int q  = lane >> 4;    // edge slot / column subset
    const int li = lane & 15;    // feature quad: feats 4li..4li+3

    const float bias0 = ldf(b1, 4*li+0, f32), bias1 = ldf(b1, 4*li+1, f32);
    const float bias2 = ldf(b1, 4*li+2, f32), bias3 = ldf(b1, 4*li+3, f32);
    float w2[4][4];
    #pragma unroll
    for (int j = 0; j < 4; ++j)
        #pragma unroll
        for (int m = 0; m < 4; ++m)
            w2[j][m] = ldf(W2, (size_t)(4*li+j)*NC + (q + 4*m), f32);

    const int wid = (blockIdx.x * blockDim.x + threadIdx.x) >> 6;
    const int nw  = (gridDim.x * blockDim.x) >> 6;
    const uint2* __restrict__ h1v = (const uint2*)h1;
    const unsigned uli = (unsigned)li;

    int row = wid;
    if (row >= NN) return;
    int beg = row_off[row];
    int end = row_off[row + 1];
    float nd = ndst[row];
    float ns = nsrc[row];

    while (row < NN) {
        // prefetch next row's descriptors; in flight during this row's gathers
        const int nrow = row + nw;
        int nbeg = 0, nend = 0;
        float nnd = 0.f, nns = 0.f;
        if (nrow < NN) {
            nbeg = row_off[nrow];
            nend = row_off[nrow + 1];
            nnd  = ndst[nrow];
            nns  = nsrc[nrow];
        }

        float ax = 0.f, ay = 0.f, az = 0.f, aw = 0.f;
        float bx = 0.f, by = 0.f, bz = 0.f, bw = 0.f;
        const int e1 = end - 1;
        int i = beg + q;
        while (i < end) {
            const int j1 = i + 4, j2 = i + 8, j3 = i + 12;
            const int t1 = (j1 < end) ? j1 : e1;
            const int t2 = (j2 < end) ? j2 : e1;
            const int t3 = (j3 < end) ? j3 : e1;
            const int s0 = srcs[(unsigned)i];
            const int s1 = srcs[(unsigned)t1];
            const int s2 = srcs[(unsigned)t2];
            const int s3 = srcs[(unsigned)t3];
            const uint2 v0 = h1v[(unsigned)s0 * 16u + uli];
            const uint2 v1 = h1v[(unsigned)s1 * 16u + uli];
            const uint2 v2 = h1v[(unsigned)s2 * 16u + uli];
            const uint2 v3 = h1v[(unsigned)s3 * 16u + uli];
            ax += bflo(v0.x); ay += bfhi(v0.x);
            az += bflo(v0.y); aw += bfhi(v0.y);
            if (j1 < end) {
                bx += bflo(v1.x); by += bfhi(v1.x);
                bz += bflo(v1.y); bw += bfhi(v1.y);
            }
            if (j2 < end) {
                ax += bflo(v2.x); ay += bfhi(v2.x);
                az += bflo(v2.y); aw += bfhi(v2.y);
            }
            if (j3 < end) {
                bx += bflo(v3.x); by += bfhi(v3.x);
                bz += bflo(v3.y); bw += bfhi(v3.y);
            }
            i += 16;
        }
        ax += bx; ay += by; az += bz; aw += bw;
        ax += __shfl_xor(ax, 16); ay += __shfl_xor(ay, 16);
        az += __shfl_xor(az, 16); aw += __shfl_xor(aw, 16);
        ax += __shfl_xor(ax, 32); ay += __shfl_xor(ay, 32);
        az += __shfl_xor(az, 32); aw += __shfl_xor(aw, 32);

        const float t0 = fmaxf(fmaf(ax, nd, bias0), 0.f);
        const float t1f = fmaxf(fmaf(ay, nd, bias1), 0.f);
        const float t2f = fmaxf(fmaf(az, nd, bias2), 0.f);
        const float t3f = fmaxf(fmaf(aw, nd, bias3), 0.f);

        float p0 = fmaf(t0,w2[0][0],fmaf(t1f,w2[1][0],fmaf(t2f,w2[2][0],t3f*w2[3][0])));
        float p1 = fmaf(t0,w2[0][1],fmaf(t1f,w2[1][1],fmaf(t2f,w2[2][1],t3f*w2[3][1])));
        float p2 = fmaf(t0,w2[0][2],fmaf(t1f,w2[1][2],fmaf(t2f,w2[2][2],t3f*w2[3][2])));
        float p3 = fmaf(t0,w2[0][3],fmaf(t1f,w2[1][3],fmaf(t2f,w2[2][3],t3f*w2[3][3])));
        #pragma unroll
        for (int off = 1; off <= 8; off <<= 1) {
            p0 += __shfl_xor(p0, off);
            p1 += __shfl_xor(p1, off);
            p2 += __shfl_xor(p2, off);
            p3 += __shfl_xor(p3, off);
        }
        if (li < 4) {
            float v = (li == 0) ? p0 : (li == 1) ? p1 : (li == 2) ? p2 : p3;
            h2[(size_t)row * NC + q + 4*li] = f2us_rn(v * ns);
        }

        row = nrow; beg = nbeg; end = nend; nd = nnd; ns = nns;
    }
}

// ---------------- fused layer-2 aggregation + bias + log_softmax ----------------
// R12 form (h2 is 3.2MB -> per-XCD-L2 resident; gathers mostly L2 hits).
__global__ __launch_bounds__(256) void k_out(
    const int* __restrict__ row_off, const int* __restrict__ srcs,
    const unsigned short* __restrict__ h2, const float* __restrict__ ndst,
    const void* __restrict__ b2, const int* __restrict__ mode,
    void* __restrict__ out)
{
    const bool f32 = (mode[0] != 0);
    const int lane = threadIdx.x & 63;
    const int q  = lane >> 3;
    const int li = lane & 7;
    const float b2v0 = ldf(b2, 2*li,   f32);
    const float b2v1 = ldf(b2, 2*li+1, f32);

    const int wid = (blockIdx.x * blockDim.x + threadIdx.x) >> 6;
    const int nw  = (gridDim.x * blockDim.x) >> 6;
    const unsigned* __restrict__ h2v = (const unsigned*)h2;
    const unsigned uli = (unsigned)li;

    int row = wid;
    if (row >= NN) return;
    int beg = row_off[row];
    int end = row_off[row + 1];
    float nd = ndst[row];

    while (row < NN) {
        const int nrow = row + nw;
        int nbeg = 0, nend = 0;
        float nnd = 0.f;
        if (nrow < NN) {
            nbeg = row_off[nrow];
            nend = row_off[nrow + 1];
            nnd  = ndst[nrow];
        }

        float a0 = 0.f, a1 = 0.f, c0 = 0.f, c1 = 0.f;
        const int e1 = end - 1;
        int i = beg + q;
        while (i < end) {
            const int j1 = i + 8;
            const int t1 = (j1 < end) ? j1 : e1;
            const int s0 = srcs[(unsigned)i];
            const int s1 = srcs[(unsigned)t1];
            const unsigned u0 = h2v[(unsigned)s0 * 8u + uli];
            const unsigned u1 = h2v[(unsigned)s1 * 8u + uli];
            a0 += bflo(u0); a1 += bfhi(u0);
            if (j1 < end) {
                c0 += bflo(u1); c1 += bfhi(u1);
            }
            i += 16;
        }
        a0 += c0; a1 += c1;
        #pragma unroll
        for (int off = 8; off <= 32; off <<= 1) {
            a0 += __shfl_xor(a0, off);
            a1 += __shfl_xor(a1, off);
        }
        float v0 = fmaf(a0, nd, b2v0);
        float v1 = fmaf(a1, nd, b2v1);
        float m = fmaxf(v0, v1);
        #pragma unroll
        for (int off = 1; off <= 4; off <<= 1) m = fmaxf(m, __shfl_xor(m, off));
        float sm = __expf(v0 - m) + __expf(v1 - m);
        #pragma unroll
        for (int off = 1; off <= 4; off <<= 1) sm += __shfl_xor(sm, off);
        const float lsm = __logf(sm);
        const float r0 = v0 - m - lsm, r1 = v1 - m - lsm;
        if (q == 0) {
            if (f32) {
                float2 o; o.x = r0; o.y = r1;
                *(float2*)((float*)out + (size_t)row * NC + 2*li) = o;
            } else {
                unsigned o = ((unsigned)f2us_rn(r1) << 16) | (unsigned)f2us_rn(r0);
                *(unsigned*)((unsigned short*)out + (size_t)row * NC + 2*li) = o;
            }
        }

        row = nrow; beg = nbeg; end = nend; nd = nnd;
    }
}

extern "C" void kernel_launch(void* const* d_in, const int* in_sizes, int n_in,
                              void* d_out, int out_size, void* d_ws, size_t ws_size,
                              hipStream_t stream) {
    const void* x  = d_in[0];
    const int* src = (const int*)d_in[1];
    const int* dst = (const int*)d_in[2];
    const void* W1 = d_in[3];
    const void* b1 = d_in[4];
    const void* W2 = d_in[5];
    const void* b2 = d_in[6];

    // ---- workspace layout (R1-identical) ----
    char* ws = (char*)d_ws;
    const size_t O_MODE = 0;                     // 1 KB
    const size_t O_W1F  = 1024;                  // fragment-ordered W1 (bf16), 16384 B
    const size_t O_CNT  = O_W1F + 16384;         // counts_d + counts_s = 401408
    const size_t O_CS   = O_CNT  + 401408;       // csum 2048 + coff 2048
    const size_t O_DEG  = O_CS   + 4096;         // 800000 (fallback only)
    const size_t O_NSRC = O_DEG  + 800000;
    const size_t O_NDST = O_NSRC + 400000;
    const size_t O_ROW  = O_NDST + 400000;       // (NN+1)*4 padded
    const size_t O_CUR  = O_ROW  + 400128;       // fallback per-node cursors
    const size_t O_BS   = O_CUR  + 400128;       // bsum 2048 + boff 2048 (fallback)
    const size_t O_SRCS = O_BS   + 4096;         // NE*4
    const size_t O_H2   = O_SRCS + 6400000;      // NN*NC*2 bf16
    const size_t O_H1   = O_H2   + 3200000;      // NN*NH*2 bf16 = 12800000
    // packed (NE*4) + packed2 (NE*2) alias into h1 (dead before gemm1)
    const size_t NEED = O_H1 + 12800000;         // ~25.2 MB
    const bool fast_csr = ws_size >= NEED;

    int*   mode     = (int*)(ws + O_MODE);
    unsigned short* W1f = (unsigned short*)(ws + O_W1F);
    int*   counts_d = (int*)(ws + O_CNT);
    int*   counts_s = counts_d + BBUK * GBIN;
    int*   csum     = (int*)(ws + O_CS);
    int*   coff     = (int*)(ws + O_CS + 2048);
    int*   deg_out  = (int*)(ws + O_DEG);
    int*   deg_in   = deg_out + NN;
    float* nsrc     = (float*)(ws + O_NSRC);
    float* ndst     = (float*)(ws + O_NDST);
    int*   row_off  = (int*)(ws + O_ROW);
    int*   cursor   = (int*)(ws + O_CUR);
    int*   bsum     = (int*)(ws + O_BS);
    int*   boff     = (int*)(ws + O_BS + 2048);
    int*   srcs_s   = (int*)(ws + O_SRCS);
    unsigned short* h2 = (unsigned short*)(ws + O_H2);
    unsigned short* h1 = (unsigned short*)(ws + O_H1);
    unsigned int*   packed  = (unsigned int*)(ws + O_H1);
    unsigned short* packed2 = (unsigned short*)(ws + O_H1 + 6400000);

    k_sniffprep<<<1, 256, 0, stream>>>((const unsigned short*)x, W1, W1f, mode);
    if (fast_csr) {
        k_hist2<<<GBIN, 256, 0, stream>>>(src, dst, counts_d, counts_s);
        k_cs_a<<<2 * NCB, 256, 0, stream>>>(counts_d, csum);
        k_cs_b2<<<1, 512, 0, stream>>>(csum, coff);
        k_cs_c<<<2 * NCB, 256, 0, stream>>>(counts_d, coff);
        k_binscatter2<<<GBIN, 256, 0, stream>>>(src, dst, counts_d, counts_s, packed, packed2);
        k_bucket2<<<BBUK, 256, 0, stream>>>(counts_d, counts_s, packed, packed2,
                                            row_off, ndst, nsrc, srcs_s);
    } else {
        hipMemsetAsync(deg_out, 0, 2 * (size_t)NN * sizeof(int), stream);
        k_deg<<<(NE / 4 + 255) / 256, 256, 0, stream>>>((const int4*)src, (const int4*)dst, deg_out, deg_in);
        k_scan_a<<<NB1, 256, 0, stream>>>(deg_in, bsum);
        k_scan_b<<<1, 512, 0, stream>>>(bsum, boff);
        k_scan_c<<<NB1, 256, 0, stream>>>(deg_in, deg_out, boff, row_off, cursor, nsrc, ndst);
        k_scatter<<<(NE + 255) / 256, 256, 0, stream>>>(src, dst, cursor, srcs_s);
    }
    k_gemm1_mfma<<<NGRP, 256, 0, stream>>>(x, W1f, nsrc, h1, mode);
    k_agg1csr<<<2048, 256, 0, stream>>>(row_off, srcs_s, h1, ndst, nsrc, b1, W2, mode, h2);
    k_out<<<2048, 256, 0, stream>>>(row_off, srcs_s, h2, ndst, b2, mode, d_out);
}

// Round 8
// 244.183 us; speedup vs baseline: 4.2783x; 1.1290x over previous
//
#include <hip/hip_runtime.h>
#include <hip/hip_bf16.h>

#define NN 100000
#define NE 1600000
#define NF 128
#define NH 64
#define NC 16
#define NB1 391    // ceil(NN/256)
#define GBIN 256   // binning workgroups
#define CHUNK 6250 // NE/GBIN
#define BBUK 196   // ceil(NN/512) coarse buckets of 512 nodes
#define NCB 196    // 256-blocks per counts array (BBUK*GBIN/256)
#define NGRP 1563  // ceil(NN/64) gemm1 row-groups

typedef __attribute__((ext_vector_type(8))) short short8v;
typedef __attribute__((ext_vector_type(4))) float float4v;

__device__ __forceinline__ float us2f(unsigned short u) {
    return __uint_as_float(((unsigned int)u) << 16);
}
__device__ __forceinline__ float bflo(unsigned u) {   // low bf16 of a packed pair
    return __uint_as_float(u << 16);
}
__device__ __forceinline__ float bfhi(unsigned u) {   // high bf16 of a packed pair
    return __uint_as_float(u & 0xFFFF0000u);
}
__device__ __forceinline__ unsigned short f2us_rn(float f) {
    unsigned int u = __float_as_uint(f);
    return (unsigned short)((u + 0x7FFFu + ((u >> 16) & 1u)) >> 16);
}
__device__ __forceinline__ float ldf(const void* p, size_t i, bool f32) {
    return f32 ? ((const float*)p)[i] : us2f(((const unsigned short*)p)[i]);
}

// ---------------- standalone sniff+prep (FALLBACK path only) ----------------
__global__ void k_sniffprep(const unsigned short* __restrict__ xu,
                            const void* __restrict__ W1,
                            unsigned short* __restrict__ W1f,
                            int* __restrict__ mode) {
    __shared__ int cnt;
    if (threadIdx.x == 0) cnt = 0;
    __syncthreads();
    int c = 0;
    for (int i = threadIdx.x; i < 4096; i += 256) {
        unsigned int e = (xu[i] >> 7) & 0xFFu;
        if (e >= 160u) c++;
    }
    atomicAdd(&cnt, c);
    __syncthreads();
    if (threadIdx.x == 0) mode[0] = (cnt >= 16) ? 1 : 0;
    __syncthreads();
    const bool f32 = (cnt >= 16);
    for (int i = threadIdx.x; i < 1024; i += 256) {
        const int kcnt = i >> 6, lane = i & 63;
        const int kc = kcnt >> 2, nt = kcnt & 3;
        const int quad = lane >> 4, col = lane & 15;
        #pragma unroll
        for (int j = 0; j < 8; ++j) {
            const size_t idx = (size_t)(kc * 32 + quad * 8 + j) * NH + nt * 16 + col;
            W1f[(size_t)i * 8 + j] = f32 ? f2us_rn(((const float*)W1)[idx])
                                         : ((const unsigned short*)W1)[idx];
        }
    }
}

// ---------------- fallback path kernels (global atomics) ----------------
__global__ void k_deg(const int4* __restrict__ src4, const int4* __restrict__ dst4,
                      int* __restrict__ deg_out, int* __restrict__ deg_in) {
    int i = blockIdx.x * blockDim.x + threadIdx.x;
    if (i < NE / 4) {
        int4 s = src4[i], d = dst4[i];
        atomicAdd(&deg_out[s.x], 1); atomicAdd(&deg_out[s.y], 1);
        atomicAdd(&deg_out[s.z], 1); atomicAdd(&deg_out[s.w], 1);
        atomicAdd(&deg_in[d.x], 1);  atomicAdd(&deg_in[d.y], 1);
        atomicAdd(&deg_in[d.z], 1);  atomicAdd(&deg_in[d.w], 1);
    }
}

__global__ void k_scatter(const int* __restrict__ src, const int* __restrict__ dst,
                          int* __restrict__ cursor, int* __restrict__ srcs_sorted) {
    int e = blockIdx.x * blockDim.x + threadIdx.x;
    if (e < NE) {
        int p = atomicAdd(&cursor[dst[e]], 1);
        srcs_sorted[p] = src[e];
    }
}

__global__ void k_scan_a(const int* __restrict__ deg_in, int* __restrict__ bsum) {
    __shared__ int s[256];
    int i = blockIdx.x * 256 + threadIdx.x;
    s[threadIdx.x] = (i < NN) ? deg_in[i] : 0;
    __syncthreads();
    for (int off = 128; off > 0; off >>= 1) {
        if (threadIdx.x < off) s[threadIdx.x] += s[threadIdx.x + off];
        __syncthreads();
    }
    if (threadIdx.x == 0) bsum[blockIdx.x] = s[0];
}

__global__ void k_scan_b(const int* __restrict__ bsum, int* __restrict__ boff) {
    __shared__ int s[512];
    int t = threadIdx.x;
    s[t] = (t < NB1) ? bsum[t] : 0;
    __syncthreads();
    for (int off = 1; off < 512; off <<= 1) {
        int v = (t >= off) ? s[t - off] : 0;
        __syncthreads();
        s[t] += v;
        __syncthreads();
    }
    if (t < NB1) boff[t] = (t == 0) ? 0 : s[t - 1];
}

__global__ void k_scan_c(const int* __restrict__ deg_in, const int* __restrict__ deg_out,
                         const int* __restrict__ boff, int* __restrict__ row_off,
                         int* __restrict__ cursor, float* __restrict__ nsrc,
                         float* __restrict__ ndst) {
    __shared__ int s[256];
    int t = threadIdx.x;
    int i = blockIdx.x * 256 + t;
    int d = (i < NN) ? deg_in[i] : 0;
    s[t] = d;
    __syncthreads();
    for (int off = 1; off < 256; off <<= 1) {
        int v = (t >= off) ? s[t - off] : 0;
        __syncthreads();
        s[t] += v;
        __syncthreads();
    }
    int excl = s[t] - d + boff[blockIdx.x];
    if (i < NN) {
        row_off[i] = excl;
        cursor[i]  = excl;
        ndst[i] = rsqrtf(fmaxf((float)d, 1.0f));
        nsrc[i] = rsqrtf(fmaxf((float)deg_out[i], 1.0f));
        if (i == NN - 1) row_off[NN] = excl + d;
    }
}

// ---------------- R19 fast CSR 1: histograms @512 threads + fused sniff/prep block ----------------
// Block GBIN (the extra block) does dtype-sniff + W1 repack; it hides inside
// the histogram blocks' execution instead of being a serial 1-block launch.
__global__ __launch_bounds__(512) void k_hist2s(const int* __restrict__ src,
                                                const int* __restrict__ dst,
                                                int* __restrict__ counts_d,
                                                int* __restrict__ counts_s,
                                                const unsigned short* __restrict__ xu,
                                                const void* __restrict__ W1,
                                                unsigned short* __restrict__ W1f,
                                                int* __restrict__ mode) {
    __shared__ int hd[BBUK], hs[BBUK];
    __shared__ int cnt;
    const int t = threadIdx.x;
    if (blockIdx.x == GBIN) {
        // ---- sniff + W1 fragment repack ----
        if (t == 0) cnt = 0;
        __syncthreads();
        int c = 0;
        for (int i = t; i < 4096; i += 512) {
            unsigned int e = (xu[i] >> 7) & 0xFFu;
            if (e >= 160u) c++;
        }
        atomicAdd(&cnt, c);
        __syncthreads();
        if (t == 0) mode[0] = (cnt >= 16) ? 1 : 0;
        __syncthreads();
        const bool f32 = (cnt >= 16);
        for (int i = t; i < 1024; i += 512) {
            const int kcnt = i >> 6, lane = i & 63;
            const int kc = kcnt >> 2, nt = kcnt & 3;
            const int quad = lane >> 4, col = lane & 15;
            #pragma unroll
            for (int j = 0; j < 8; ++j) {
                const size_t idx = (size_t)(kc * 32 + quad * 8 + j) * NH + nt * 16 + col;
                W1f[(size_t)i * 8 + j] = f32 ? f2us_rn(((const float*)W1)[idx])
                                             : ((const unsigned short*)W1)[idx];
            }
        }
        return;
    }
    // ---- per-(bucket,group) histograms, 512 threads (8 waves/CU vs 4) ----
    for (int i = t; i < BBUK; i += 512) { hd[i] = 0; hs[i] = 0; }
    __syncthreads();
    const int g = blockIdx.x;
    const int e0 = g * CHUNK;
    for (int i = t; i < CHUNK; i += 512) {
        atomicAdd(&hd[dst[e0 + i] >> 9], 1);
        atomicAdd(&hs[src[e0 + i] >> 9], 1);
    }
    __syncthreads();
    for (int i = t; i < BBUK; i += 512) {
        counts_d[i * GBIN + g] = hd[i];
        counts_s[i * GBIN + g] = hs[i];
    }
}

// ---------------- fast CSR 2a: per-256-block sums ----------------
__global__ void k_cs_a(const int* __restrict__ counts, int* __restrict__ csum) {
    __shared__ int s[256];
    int i = blockIdx.x * 256 + threadIdx.x;
    s[threadIdx.x] = counts[i];
    __syncthreads();
    for (int off = 128; off > 0; off >>= 1) {
        if (threadIdx.x < off) s[threadIdx.x] += s[threadIdx.x + off];
        __syncthreads();
    }
    if (threadIdx.x == 0) csum[blockIdx.x] = s[0];
}

// ---------------- R19 fast CSR 2b: intra-block scan with SELF-COMPUTED offset ----------------
// Replaces cs_b2 + cs_c: each block redundantly prefix-sums csum for its half
// (<=196 loads + LDS reduce) instead of a serial 1-block scan kernel.
__global__ void k_cs_c(int* __restrict__ counts, const int* __restrict__ csum) {
    __shared__ int s[256];
    const int t = threadIdx.x;
    const int blk = blockIdx.x;                 // 0..2*NCB-1
    const int half = (blk >= NCB) ? 1 : 0;
    const int j = blk - half * NCB;             // block index within its half
    // exclusive offset = sum of csum[half*NCB + k] for k < j   (j <= 195)
    s[t] = (t < j) ? csum[half * NCB + t] : 0;
    __syncthreads();
    for (int off = 128; off > 0; off >>= 1) {
        if (t < off) s[t] += s[t + off];
        __syncthreads();
    }
    const int blockoff = s[0];
    __syncthreads();
    // intra-block inclusive scan -> exclusive + offset
    const int i = blk * 256 + t;
    const int v = counts[i];
    s[t] = v;
    __syncthreads();
    for (int off = 1; off < 256; off <<= 1) {
        int u = (t >= off) ? s[t - off] : 0;
        __syncthreads();
        s[t] += u;
        __syncthreads();
    }
    counts[i] = s[t] - v + blockoff;
}

// ---------------- fast CSR 3: private-slice binning @512 threads ----------------
__global__ __launch_bounds__(512) void k_binscatter2(const int* __restrict__ src,
                                                     const int* __restrict__ dst,
                                                     const int* __restrict__ counts_d,
                                                     const int* __restrict__ counts_s,
                                                     unsigned int* __restrict__ packed,
                                                     unsigned short* __restrict__ packed2) {
    __shared__ int curd[BBUK], curs[BBUK];
    const int t = threadIdx.x;
    const int g = blockIdx.x;
    for (int i = t; i < BBUK; i += 512) {
        curd[i] = counts_d[i * GBIN + g];
        curs[i] = counts_s[i * GBIN + g];
    }
    __syncthreads();
    const int e0 = g * CHUNK;
    for (int i = t; i < CHUNK; i += 512) {
        int s = src[e0 + i], d = dst[e0 + i];
        int pd = atomicAdd(&curd[d >> 9], 1);
        packed[pd] = ((unsigned)s << 9) | (unsigned)(d & 511);
        int ps = atomicAdd(&curs[s >> 9], 1);
        packed2[ps] = (unsigned short)(s & 511);
    }
}

// ---------------- R19 fast CSR 4+5 fused, @512 threads ----------------
// Phase 1: out-degree histogram over packed2 -> nsrc.
// Phase 2: in-deg histogram + 512-elem Blelloch scan + row_off/ndst + scatter.
__global__ __launch_bounds__(512) void k_bucket2(const int* __restrict__ counts_d,
                                                 const int* __restrict__ counts_s,
                                                 const unsigned int* __restrict__ packed,
                                                 const unsigned short* __restrict__ packed2,
                                                 int* __restrict__ row_off,
                                                 float* __restrict__ ndst,
                                                 float* __restrict__ nsrc,
                                                 int* __restrict__ srcs_sorted) {
    __shared__ int h[512];
    const int b = blockIdx.x;
    const int n0 = b << 9;
    const int nlim = (NN - n0 < 512) ? (NN - n0) : 512;
    const int t = threadIdx.x;   // 0..511

    // ---- phase 1: src-side out-degree -> nsrc ----
    h[t] = 0;
    __syncthreads();
    {
        const int sbeg = counts_s[b * GBIN];
        const int send = (b + 1 < BBUK) ? counts_s[(b + 1) * GBIN] : NE;
        for (int i = sbeg + t; i < send; i += 512)
            atomicAdd(&h[packed2[i] & 511u], 1);
    }
    __syncthreads();
    if (t < nlim) nsrc[n0 + t] = rsqrtf(fmaxf((float)h[t], 1.0f));
    __syncthreads();

    // ---- phase 2: dst-side CSR build ----
    h[t] = 0;
    __syncthreads();
    const int beg = counts_d[b * GBIN];
    const int end = (b + 1 < BBUK) ? counts_d[(b + 1) * GBIN] : NE;
    for (int i = beg + t; i < end; i += 512)
        atomicAdd(&h[packed[i] & 511u], 1);
    __syncthreads();
    const int deg = h[t];                  // this thread's node in-degree
    // Blelloch exclusive scan of 512 elems (512 threads; t<d masks work)
    int offset = 1;
    #pragma unroll
    for (int d = 256; d > 0; d >>= 1) {
        __syncthreads();
        if (t < d) {
            int ai = offset * (2 * t + 1) - 1;
            int bi = offset * (2 * t + 2) - 1;
            h[bi] += h[ai];
        }
        offset <<= 1;
    }
    __syncthreads();
    if (t == 0) h[511] = 0;
    #pragma unroll
    for (int d = 1; d < 512; d <<= 1) {
        offset >>= 1;
        __syncthreads();
        if (t < d) {
            int ai = offset * (2 * t + 1) - 1;
            int bi = offset * (2 * t + 2) - 1;
            int tmp = h[ai]; h[ai] = h[bi]; h[bi] += tmp;
        }
    }
    __syncthreads();
    const int r0 = beg + h[t];
    if (t < nlim) {
        row_off[n0 + t] = r0;
        ndst[n0 + t] = rsqrtf(fmaxf((float)deg, 1.0f));
    }
    if (n0 + nlim == NN && t == 0) row_off[NN] = end;
    __syncthreads();
    h[t] = r0;                             // LDS cursors
    __syncthreads();
    for (int i = beg + t; i < end; i += 512) {
        unsigned v = packed[i];
        int p = atomicAdd(&h[v & 511u], 1);
        srcs_sorted[p] = (int)(v >> 9);
    }
}

// ---------------- layer 1 GEMM (MFMA, both dtypes) ----------------
__global__ __launch_bounds__(256) void k_gemm1_mfma(
    const void* __restrict__ x, const unsigned short* __restrict__ W1f,
    const float* __restrict__ nsrc, unsigned short* __restrict__ h1,
    const int* __restrict__ mode)
{
    const bool f32 = (mode[0] != 0);
    const int tid = threadIdx.x;
    const int wave = tid >> 6, lane = tid & 63;
    const int col = lane & 15, quad = lane >> 4;

    short8v bfrag[16];
    #pragma unroll
    for (int f = 0; f < 16; ++f)
        bfrag[f] = *(const short8v*)(W1f + ((size_t)f * 64 + lane) * 8);

    const int base = blockIdx.x * 64 + wave * 16;
    int arow = base + col;
    if (arow > NN - 1) arow = NN - 1;

    short8v afrag[4];
    if (f32) {
        const float4* ap = (const float4*)((const float*)x + (size_t)arow * NF);
        #pragma unroll
        for (int kc = 0; kc < 4; ++kc) {
            float4 v0 = ap[kc * 8 + quad * 2];
            float4 v1 = ap[kc * 8 + quad * 2 + 1];
            short8v af;
            af[0] = (short)f2us_rn(v0.x); af[1] = (short)f2us_rn(v0.y);
            af[2] = (short)f2us_rn(v0.z); af[3] = (short)f2us_rn(v0.w);
            af[4] = (short)f2us_rn(v1.x); af[5] = (short)f2us_rn(v1.y);
            af[6] = (short)f2us_rn(v1.z); af[7] = (short)f2us_rn(v1.w);
            afrag[kc] = af;
        }
    } else {
        const uint4* ap = (const uint4*)((const unsigned short*)x + (size_t)arow * NF);
        #pragma unroll
        for (int kc = 0; kc < 4; ++kc) {
            uint4 v = ap[kc * 4 + quad];
            afrag[kc] = *reinterpret_cast<const short8v*>(&v);
        }
    }

    float4v acc[4];
    #pragma unroll
    for (int nt = 0; nt < 4; ++nt) acc[nt] = (float4v){0.f, 0.f, 0.f, 0.f};
    #pragma unroll
    for (int kc = 0; kc < 4; ++kc)
        #pragma unroll
        for (int nt = 0; nt < 4; ++nt)
            acc[nt] = __builtin_amdgcn_mfma_f32_16x16x32_bf16(afrag[kc], bfrag[kc * 4 + nt], acc[nt], 0, 0, 0);

    #pragma unroll
    for (int reg = 0; reg < 4; ++reg) {
        const int row = base + quad * 4 + reg;
        if (row < NN) {
            const float ns = nsrc[row];
            unsigned short* hp = h1 + (size_t)row * NH + col;
            hp[0]  = f2us_rn(acc[0][reg] * ns);
            hp[16] = f2us_rn(acc[1][reg] * ns);
            hp[32] = f2us_rn(acc[2][reg] * ns);
            hp[48] = f2us_rn(acc[3][reg] * ns);
        }
    }
}

// ---------------- fused layer-1 aggregation + relu + W2 GEMM ----------------
// R12 body - FROZEN. History: R11 wider slots 70us, R13 two-row 71us, R14
// gload_lds prefetch 98us, R17 bucket-LDS 700us - all reverted. 60us = this
// gather structure's floor: 89MB L2-miss traffic (mostly L3-hit) at 1.46 TB/s,
// MSHR/concurrency bound; more per-wave MLP only lengthens in-order vmcnt
// drain chains.
__global__ __launch_bounds__(256) void k_agg1csr(
    const int* __restrict__ row_off, const int* __restrict__ srcs,
    const unsigned short* __restrict__ h1, const float* __restrict__ ndst,
    const float* __restrict__ nsrc, const void* __restrict__ b1,
    const void* __restrict__ W2, const int* __restrict__ mode,
    unsigned short* __restrict__ h2)
{
    const bool f32 = (mode[0] != 0);
    const int lane = threadIdx.x & 63;
    const int q  = lane >> 4;    // edge slot / column subset
    const int li = lane & 15;    // feature quad: feats 4li..4li+3

    const float bias0 = ldf(b1, 4*li+0, f32), bias1 = ldf(b1, 4*li+1, f32);
    const float bias2 = ldf(b1, 4*li+2, f32), bias3 = ldf(b1, 4*li+3, f32);
    float w2[4][4];
    #pragma unroll
    for (int j = 0; j < 4; ++j)
        #pragma unroll
        for (int m = 0; m < 4; ++m)
            w2[j][m] = ldf(W2, (size_t)(4*li+j)*NC + (q + 4*m), f32);

    const int wid = (blockIdx.x * blockDim.x + threadIdx.x) >> 6;
    const int nw  = (gridDim.x * blockDim.x) >> 6;
    const uint2* __restrict__ h1v = (const uint2*)h1;
    const unsigned uli = (unsigned)li;

    int row = wid;
    if (row >= NN) return;
    int beg = row_off[row];
    int end = row_off[row + 1];
    float nd = ndst[row];
    float ns = nsrc[row];

    while (row < NN) {
        // prefetch next row's descriptors; in flight during this row's gathers
        const int nrow = row + nw;
        int nbeg = 0, nend = 0;
        float nnd = 0.f, nns = 0.f;
        if (nrow < NN) {
            nbeg = row_off[nrow];
            nend = row_off[nrow + 1];
            nnd  = ndst[nrow];
            nns  = nsrc[nrow];
        }

        float ax = 0.f, ay = 0.f, az = 0.f, aw = 0.f;
        float bx = 0.f, by = 0.f, bz = 0.f, bw = 0.f;
        const int e1 = end - 1;
        int i = beg + q;
        while (i < end) {
            const int j1 = i + 4, j2 = i + 8, j3 = i + 12;
            const int t1 = (j1 < end) ? j1 : e1;
            const int t2 = (j2 < end) ? j2 : e1;
            const int t3 = (j3 < end) ? j3 : e1;
            const int s0 = srcs[(unsigned)i];
            const int s1 = srcs[(unsigned)t1];
            const int s2 = srcs[(unsigned)t2];
            const int s3 = srcs[(unsigned)t3];
            const uint2 v0 = h1v[(unsigned)s0 * 16u + uli];
            const uint2 v1 = h1v[(unsigned)s1 * 16u + uli];
            const uint2 v2 = h1v[(unsigned)s2 * 16u + uli];
            const uint2 v3 = h1v[(unsigned)s3 * 16u + uli];
            ax += bflo(v0.x); ay += bfhi(v0.x);
            az += bflo(v0.y); aw += bfhi(v0.y);
            if (j1 < end) {
                bx += bflo(v1.x); by += bfhi(v1.x);
                bz += bflo(v1.y); bw += bfhi(v1.y);
            }
            if (j2 < end) {
                ax += bflo(v2.x); ay += bfhi(v2.x);
                az += bflo(v2.y); aw += bfhi(v2.y);
            }
            if (j3 < end) {
                bx += bflo(v3.x); by += bfhi(v3.x);
                bz += bflo(v3.y); bw += bfhi(v3.y);
            }
            i += 16;
        }
        ax += bx; ay += by; az += bz; aw += bw;
        ax += __shfl_xor(ax, 16); ay += __shfl_xor(ay, 16);
        az += __shfl_xor(az, 16); aw += __shfl_xor(aw, 16);
        ax += __shfl_xor(ax, 32); ay += __shfl_xor(ay, 32);
        az += __shfl_xor(az, 32); aw += __shfl_xor(aw, 32);

        const float t0 = fmaxf(fmaf(ax, nd, bias0), 0.f);
        const float t1f = fmaxf(fmaf(ay, nd, bias1), 0.f);
        const float t2f = fmaxf(fmaf(az, nd, bias2), 0.f);
        const float t3f = fmaxf(fmaf(aw, nd, bias3), 0.f);

        float p0 = fmaf(t0,w2[0][0],fmaf(t1f,w2[1][0],fmaf(t2f,w2[2][0],t3f*w2[3][0])));
        float p1 = fmaf(t0,w2[0][1],fmaf(t1f,w2[1][1],fmaf(t2f,w2[2][1],t3f*w2[3][1])));
        float p2 = fmaf(t0,w2[0][2],fmaf(t1f,w2[1][2],fmaf(t2f,w2[2][2],t3f*w2[3][2])));
        float p3 = fmaf(t0,w2[0][3],fmaf(t1f,w2[1][3],fmaf(t2f,w2[2][3],t3f*w2[3][3])));
        #pragma unroll
        for (int off = 1; off <= 8; off <<= 1) {
            p0 += __shfl_xor(p0, off);
            p1 += __shfl_xor(p1, off);
            p2 += __shfl_xor(p2, off);
            p3 += __shfl_xor(p3, off);
        }
        if (li < 4) {
            float v = (li == 0) ? p0 : (li == 1) ? p1 : (li == 2) ? p2 : p3;
            h2[(size_t)row * NC + q + 4*li] = f2us_rn(v * ns);
        }

        row = nrow; beg = nbeg; end = nend; nd = nnd; ns = nns;
    }
}

// ---------------- fused layer-2 aggregation + bias + log_softmax ----------------
// R12 form (h2 is 3.2MB -> per-XCD-L2 resident; gathers mostly L2 hits).
__global__ __launch_bounds__(256) void k_out(
    const int* __restrict__ row_off, const int* __restrict__ srcs,
    const unsigned short* __restrict__ h2, const float* __restrict__ ndst,
    const void* __restrict__ b2, const int* __restrict__ mode,
    void* __restrict__ out)
{
    const bool f32 = (mode[0] != 0);
    const int lane = threadIdx.x & 63;
    const int q  = lane >> 3;
    const int li = lane & 7;
    const float b2v0 = ldf(b2, 2*li,   f32);
    const float b2v1 = ldf(b2, 2*li+1, f32);

    const int wid = (blockIdx.x * blockDim.x + threadIdx.x) >> 6;
    const int nw  = (gridDim.x * blockDim.x) >> 6;
    const unsigned* __restrict__ h2v = (const unsigned*)h2;
    const unsigned uli = (unsigned)li;

    int row = wid;
    if (row >= NN) return;
    int beg = row_off[row];
    int end = row_off[row + 1];
    float nd = ndst[row];

    while (row < NN) {
        const int nrow = row + nw;
        int nbeg = 0, nend = 0;
        float nnd = 0.f;
        if (nrow < NN) {
            nbeg = row_off[nrow];
            nend = row_off[nrow + 1];
            nnd  = ndst[nrow];
        }

        float a0 = 0.f, a1 = 0.f, c0 = 0.f, c1 = 0.f;
        const int e1 = end - 1;
        int i = beg + q;
        while (i < end) {
            const int j1 = i + 8;
            const int t1 = (j1 < end) ? j1 : e1;
            const int s0 = srcs[(unsigned)i];
            const int s1 = srcs[(unsigned)t1];
            const unsigned u0 = h2v[(unsigned)s0 * 8u + uli];
            const unsigned u1 = h2v[(unsigned)s1 * 8u + uli];
            a0 += bflo(u0); a1 += bfhi(u0);
            if (j1 < end) {
                c0 += bflo(u1); c1 += bfhi(u1);
            }
            i += 16;
        }
        a0 += c0; a1 += c1;
        #pragma unroll
        for (int off = 8; off <= 32; off <<= 1) {
            a0 += __shfl_xor(a0, off);
            a1 += __shfl_xor(a1, off);
        }
        float v0 = fmaf(a0, nd, b2v0);
        float v1 = fmaf(a1, nd, b2v1);
        float m = fmaxf(v0, v1);
        #pragma unroll
        for (int off = 1; off <= 4; off <<= 1) m = fmaxf(m, __shfl_xor(m, off));
        float sm = __expf(v0 - m) + __expf(v1 - m);
        #pragma unroll
        for (int off = 1; off <= 4; off <<= 1) sm += __shfl_xor(sm, off);
        const float lsm = __logf(sm);
        const float r0 = v0 - m - lsm, r1 = v1 - m - lsm;
        if (q == 0) {
            if (f32) {
                float2 o; o.x = r0; o.y = r1;
                *(float2*)((float*)out + (size_t)row * NC + 2*li) = o;
            } else {
                unsigned o = ((unsigned)f2us_rn(r1) << 16) | (unsigned)f2us_rn(r0);
                *(unsigned*)((unsigned short*)out + (size_t)row * NC + 2*li) = o;
            }
        }

        row = nrow; beg = nbeg; end = nend; nd = nnd;
    }
}

extern "C" void kernel_launch(void* const* d_in, const int* in_sizes, int n_in,
                              void* d_out, int out_size, void* d_ws, size_t ws_size,
                              hipStream_t stream) {
    const void* x  = d_in[0];
    const int* src = (const int*)d_in[1];
    const int* dst = (const int*)d_in[2];
    const void* W1 = d_in[3];
    const void* b1 = d_in[4];
    const void* W2 = d_in[5];
    const void* b2 = d_in[6];

    // ---- workspace layout (R1-identical) ----
    char* ws = (char*)d_ws;
    const size_t O_MODE = 0;                     // 1 KB
    const size_t O_W1F  = 1024;                  // fragment-ordered W1 (bf16), 16384 B
    const size_t O_CNT  = O_W1F + 16384;         // counts_d + counts_s = 401408
    const size_t O_CS   = O_CNT  + 401408;       // csum 2048 + coff 2048
    const size_t O_DEG  = O_CS   + 4096;         // 800000 (fallback only)
    const size_t O_NSRC = O_DEG  + 800000;
    const size_t O_NDST = O_NSRC + 400000;
    const size_t O_ROW  = O_NDST + 400000;       // (NN+1)*4 padded
    const size_t O_CUR  = O_ROW  + 400128;       // fallback per-node cursors
    const size_t O_BS   = O_CUR  + 400128;       // bsum 2048 + boff 2048 (fallback)
    const size_t O_SRCS = O_BS   + 4096;         // NE*4
    const size_t O_H2   = O_SRCS + 6400000;      // NN*NC*2 bf16
    const size_t O_H1   = O_H2   + 3200000;      // NN*NH*2 bf16 = 12800000
    // packed (NE*4) + packed2 (NE*2) alias into h1 (dead before gemm1)
    const size_t NEED = O_H1 + 12800000;         // ~25.2 MB
    const bool fast_csr = ws_size >= NEED;

    int*   mode     = (int*)(ws + O_MODE);
    unsigned short* W1f = (unsigned short*)(ws + O_W1F);
    int*   counts_d = (int*)(ws + O_CNT);
    int*   counts_s = counts_d + BBUK * GBIN;
    int*   csum     = (int*)(ws + O_CS);
    int*   coff     = (int*)(ws + O_CS + 2048);
    int*   deg_out  = (int*)(ws + O_DEG);
    int*   deg_in   = deg_out + NN;
    float* nsrc     = (float*)(ws + O_NSRC);
    float* ndst     = (float*)(ws + O_NDST);
    int*   row_off  = (int*)(ws + O_ROW);
    int*   cursor   = (int*)(ws + O_CUR);
    int*   bsum     = (int*)(ws + O_BS);
    int*   boff     = (int*)(ws + O_BS + 2048);
    int*   srcs_s   = (int*)(ws + O_SRCS);
    unsigned short* h2 = (unsigned short*)(ws + O_H2);
    unsigned short* h1 = (unsigned short*)(ws + O_H1);
    unsigned int*   packed  = (unsigned int*)(ws + O_H1);
    unsigned short* packed2 = (unsigned short*)(ws + O_H1 + 6400000);

    if (fast_csr) {
        k_hist2s<<<GBIN + 1, 512, 0, stream>>>(src, dst, counts_d, counts_s,
                                               (const unsigned short*)x, W1, W1f, mode);
        k_cs_a<<<2 * NCB, 256, 0, stream>>>(counts_d, csum);
        k_cs_c<<<2 * NCB, 256, 0, stream>>>(counts_d, csum);
        k_binscatter2<<<GBIN, 512, 0, stream>>>(src, dst, counts_d, counts_s, packed, packed2);
        k_bucket2<<<BBUK, 512, 0, stream>>>(counts_d, counts_s, packed, packed2,
                                            row_off, ndst, nsrc, srcs_s);
    } else {
        k_sniffprep<<<1, 256, 0, stream>>>((const unsigned short*)x, W1, W1f, mode);
        hipMemsetAsync(deg_out, 0, 2 * (size_t)NN * sizeof(int), stream);
        k_deg<<<(NE / 4 + 255) / 256, 256, 0, stream>>>((const int4*)src, (const int4*)dst, deg_out, deg_in);
        k_scan_a<<<NB1, 256, 0, stream>>>(deg_in, bsum);
        k_scan_b<<<1, 512, 0, stream>>>(bsum, boff);
        k_scan_c<<<NB1, 256, 0, stream>>>(deg_in, deg_out, boff, row_off, cursor, nsrc, ndst);
        k_scatter<<<(NE + 255) / 256, 256, 0, stream>>>(src, dst, cursor, srcs_s);
    }
    k_gemm1_mfma<<<NGRP, 256, 0, stream>>>(x, W1f, nsrc, h1, mode);
    k_agg1csr<<<2048, 256, 0, stream>>>(row_off, srcs_s, h1, ndst, nsrc, b1, W2, mode, h2);
    k_out<<<2048, 256, 0, stream>>>(row_off, srcs_s, h2, ndst, b2, mode, d_out);
}

// Round 10
// 235.945 us; speedup vs baseline: 4.4277x; 1.0349x over previous
//
#include <hip/hip_runtime.h>
#include <hip/hip_bf16.h>

#define NN 100000
#define NE 1600000
#define NF 128
#define NH 64
#define NC 16
#define NB1 391    // ceil(NN/256)
#define GBIN 256   // binning workgroups
#define CHUNK 6250 // NE/GBIN
#define BBUK 196   // ceil(NN/512) coarse buckets of 512 nodes
#define NCB 196    // 256-blocks per counts array (BBUK*GBIN/256)
#define NGRP 1563  // ceil(NN/64) gemm1 row-groups

typedef __attribute__((ext_vector_type(8))) short short8v;
typedef __attribute__((ext_vector_type(4))) float float4v;

__device__ __forceinline__ float us2f(unsigned short u) {
    return __uint_as_float(((unsigned int)u) << 16);
}
__device__ __forceinline__ float bflo(unsigned u) {   // low bf16 of a packed pair
    return __uint_as_float(u << 16);
}
__device__ __forceinline__ float bfhi(unsigned u) {   // high bf16 of a packed pair
    return __uint_as_float(u & 0xFFFF0000u);
}
__device__ __forceinline__ unsigned short f2us_rn(float f) {
    unsigned int u = __float_as_uint(f);
    return (unsigned short)((u + 0x7FFFu + ((u >> 16) & 1u)) >> 16);
}
__device__ __forceinline__ float ldf(const void* p, size_t i, bool f32) {
    return f32 ? ((const float*)p)[i] : us2f(((const unsigned short*)p)[i]);
}

// ---------------- standalone sniff+prep (FALLBACK path only) ----------------
__global__ void k_sniffprep(const unsigned short* __restrict__ xu,
                            const void* __restrict__ W1,
                            unsigned short* __restrict__ W1f,
                            int* __restrict__ mode) {
    __shared__ int cnt;
    if (threadIdx.x == 0) cnt = 0;
    __syncthreads();
    int c = 0;
    for (int i = threadIdx.x; i < 4096; i += 256) {
        unsigned int e = (xu[i] >> 7) & 0xFFu;
        if (e >= 160u) c++;
    }
    atomicAdd(&cnt, c);
    __syncthreads();
    if (threadIdx.x == 0) mode[0] = (cnt >= 16) ? 1 : 0;
    __syncthreads();
    const bool f32 = (cnt >= 16);
    for (int i = threadIdx.x; i < 1024; i += 256) {
        const int kcnt = i >> 6, lane = i & 63;
        const int kc = kcnt >> 2, nt = kcnt & 3;
        const int quad = lane >> 4, col = lane & 15;
        #pragma unroll
        for (int j = 0; j < 8; ++j) {
            const size_t idx = (size_t)(kc * 32 + quad * 8 + j) * NH + nt * 16 + col;
            W1f[(size_t)i * 8 + j] = f32 ? f2us_rn(((const float*)W1)[idx])
                                         : ((const unsigned short*)W1)[idx];
        }
    }
}

// ---------------- fallback path kernels (global atomics) ----------------
__global__ void k_deg(const int4* __restrict__ src4, const int4* __restrict__ dst4,
                      int* __restrict__ deg_out, int* __restrict__ deg_in) {
    int i = blockIdx.x * blockDim.x + threadIdx.x;
    if (i < NE / 4) {
        int4 s = src4[i], d = dst4[i];
        atomicAdd(&deg_out[s.x], 1); atomicAdd(&deg_out[s.y], 1);
        atomicAdd(&deg_out[s.z], 1); atomicAdd(&deg_out[s.w], 1);
        atomicAdd(&deg_in[d.x], 1);  atomicAdd(&deg_in[d.y], 1);
        atomicAdd(&deg_in[d.z], 1);  atomicAdd(&deg_in[d.w], 1);
    }
}

__global__ void k_scatter(const int* __restrict__ src, const int* __restrict__ dst,
                          int* __restrict__ cursor, int* __restrict__ srcs_sorted) {
    int e = blockIdx.x * blockDim.x + threadIdx.x;
    if (e < NE) {
        int p = atomicAdd(&cursor[dst[e]], 1);
        srcs_sorted[p] = src[e];
    }
}

__global__ void k_scan_a(const int* __restrict__ deg_in, int* __restrict__ bsum) {
    __shared__ int s[256];
    int i = blockIdx.x * 256 + threadIdx.x;
    s[threadIdx.x] = (i < NN) ? deg_in[i] : 0;
    __syncthreads();
    for (int off = 128; off > 0; off >>= 1) {
        if (threadIdx.x < off) s[threadIdx.x] += s[threadIdx.x + off];
        __syncthreads();
    }
    if (threadIdx.x == 0) bsum[blockIdx.x] = s[0];
}

__global__ void k_scan_b(const int* __restrict__ bsum, int* __restrict__ boff) {
    __shared__ int s[512];
    int t = threadIdx.x;
    s[t] = (t < NB1) ? bsum[t] : 0;
    __syncthreads();
    for (int off = 1; off < 512; off <<= 1) {
        int v = (t >= off) ? s[t - off] : 0;
        __syncthreads();
        s[t] += v;
        __syncthreads();
    }
    if (t < NB1) boff[t] = (t == 0) ? 0 : s[t - 1];
}

__global__ void k_scan_c(const int* __restrict__ deg_in, const int* __restrict__ deg_out,
                         const int* __restrict__ boff, int* __restrict__ row_off,
                         int* __restrict__ cursor, float* __restrict__ nsrc,
                         float* __restrict__ ndst) {
    __shared__ int s[256];
    int t = threadIdx.x;
    int i = blockIdx.x * 256 + t;
    int d = (i < NN) ? deg_in[i] : 0;
    s[t] = d;
    __syncthreads();
    for (int off = 1; off < 256; off <<= 1) {
        int v = (t >= off) ? s[t - off] : 0;
        __syncthreads();
        s[t] += v;
        __syncthreads();
    }
    int excl = s[t] - d + boff[blockIdx.x];
    if (i < NN) {
        row_off[i] = excl;
        cursor[i]  = excl;
        ndst[i] = rsqrtf(fmaxf((float)d, 1.0f));
        nsrc[i] = rsqrtf(fmaxf((float)deg_out[i], 1.0f));
        if (i == NN - 1) row_off[NN] = excl + d;
    }
}

// ---------------- R20 fast CSR 1: histograms @1024 threads + fused sniff/prep block ----------------
// R19: 256->512 threads was +; these 256-ish-block kernels run ~1 block/CU, so
// block size IS the wave-occupancy lever (R15's GBIN growth is the wrong lever).
// 1024 threads -> 16 waves/CU (50% of capacity).
__global__ __launch_bounds__(1024) void k_hist2s(const int* __restrict__ src,
                                                 const int* __restrict__ dst,
                                                 int* __restrict__ counts_d,
                                                 int* __restrict__ counts_s,
                                                 const unsigned short* __restrict__ xu,
                                                 const void* __restrict__ W1,
                                                 unsigned short* __restrict__ W1f,
                                                 int* __restrict__ mode) {
    __shared__ int hd[BBUK], hs[BBUK];
    __shared__ int cnt;
    const int t = threadIdx.x;
    if (blockIdx.x == GBIN) {
        // ---- sniff + W1 fragment repack ----
        if (t == 0) cnt = 0;
        __syncthreads();
        int c = 0;
        for (int i = t; i < 4096; i += 1024) {
            unsigned int e = (xu[i] >> 7) & 0xFFu;
            if (e >= 160u) c++;
        }
        atomicAdd(&cnt, c);
        __syncthreads();
        if (t == 0) mode[0] = (cnt >= 16) ? 1 : 0;
        __syncthreads();
        const bool f32 = (cnt >= 16);
        for (int i = t; i < 1024; i += 1024) {
            const int kcnt = i >> 6, lane = i & 63;
            const int kc = kcnt >> 2, nt = kcnt & 3;
            const int quad = lane >> 4, col = lane & 15;
            #pragma unroll
            for (int j = 0; j < 8; ++j) {
                const size_t idx = (size_t)(kc * 32 + quad * 8 + j) * NH + nt * 16 + col;
                W1f[(size_t)i * 8 + j] = f32 ? f2us_rn(((const float*)W1)[idx])
                                             : ((const unsigned short*)W1)[idx];
            }
        }
        return;
    }
    // ---- per-(bucket,group) histograms ----
    for (int i = t; i < BBUK; i += 1024) { hd[i] = 0; hs[i] = 0; }
    __syncthreads();
    const int g = blockIdx.x;
    const int e0 = g * CHUNK;
    for (int i = t; i < CHUNK; i += 1024) {
        atomicAdd(&hd[dst[e0 + i] >> 9], 1);
        atomicAdd(&hs[src[e0 + i] >> 9], 1);
    }
    __syncthreads();
    for (int i = t; i < BBUK; i += 1024) {
        counts_d[i * GBIN + g] = hd[i];
        counts_s[i * GBIN + g] = hs[i];
    }
}

// ---------------- fast CSR 2a: per-256-block sums ----------------
__global__ void k_cs_a(const int* __restrict__ counts, int* __restrict__ csum) {
    __shared__ int s[256];
    int i = blockIdx.x * 256 + threadIdx.x;
    s[threadIdx.x] = counts[i];
    __syncthreads();
    for (int off = 128; off > 0; off >>= 1) {
        if (threadIdx.x < off) s[threadIdx.x] += s[threadIdx.x + off];
        __syncthreads();
    }
    if (threadIdx.x == 0) csum[blockIdx.x] = s[0];
}

// ---------------- R19 fast CSR 2b: intra-block scan with SELF-COMPUTED offset ----------------
__global__ void k_cs_c(int* __restrict__ counts, const int* __restrict__ csum) {
    __shared__ int s[256];
    const int t = threadIdx.x;
    const int blk = blockIdx.x;                 // 0..2*NCB-1
    const int half = (blk >= NCB) ? 1 : 0;
    const int j = blk - half * NCB;             // block index within its half
    s[t] = (t < j) ? csum[half * NCB + t] : 0;
    __syncthreads();
    for (int off = 128; off > 0; off >>= 1) {
        if (t < off) s[t] += s[t + off];
        __syncthreads();
    }
    const int blockoff = s[0];
    __syncthreads();
    const int i = blk * 256 + t;
    const int v = counts[i];
    s[t] = v;
    __syncthreads();
    for (int off = 1; off < 256; off <<= 1) {
        int u = (t >= off) ? s[t - off] : 0;
        __syncthreads();
        s[t] += u;
        __syncthreads();
    }
    counts[i] = s[t] - v + blockoff;
}

// ---------------- R20 fast CSR 3: private-slice binning @1024 threads ----------------
__global__ __launch_bounds__(1024) void k_binscatter2(const int* __restrict__ src,
                                                      const int* __restrict__ dst,
                                                      const int* __restrict__ counts_d,
                                                      const int* __restrict__ counts_s,
                                                      unsigned int* __restrict__ packed,
                                                      unsigned short* __restrict__ packed2) {
    __shared__ int curd[BBUK], curs[BBUK];
    const int t = threadIdx.x;
    const int g = blockIdx.x;
    for (int i = t; i < BBUK; i += 1024) {
        curd[i] = counts_d[i * GBIN + g];
        curs[i] = counts_s[i * GBIN + g];
    }
    __syncthreads();
    const int e0 = g * CHUNK;
    for (int i = t; i < CHUNK; i += 1024) {
        int s = src[e0 + i], d = dst[e0 + i];
        int pd = atomicAdd(&curd[d >> 9], 1);
        packed[pd] = ((unsigned)s << 9) | (unsigned)(d & 511);
        int ps = atomicAdd(&curs[s >> 9], 1);
        packed2[ps] = (unsigned short)(s & 511);
    }
}

// ---------------- R20 fast CSR 4+5 fused, @1024 threads ----------------
// Scan section stays 512-wide (t<512 guards, uniform barriers); the atomic
// histogram / scatter loops use all 16 waves.
__global__ __launch_bounds__(1024) void k_bucket2(const int* __restrict__ counts_d,
                                                  const int* __restrict__ counts_s,
                                                  const unsigned int* __restrict__ packed,
                                                  const unsigned short* __restrict__ packed2,
                                                  int* __restrict__ row_off,
                                                  float* __restrict__ ndst,
                                                  float* __restrict__ nsrc,
                                                  int* __restrict__ srcs_sorted) {
    __shared__ int h[512];
    const int b = blockIdx.x;
    const int n0 = b << 9;
    const int nlim = (NN - n0 < 512) ? (NN - n0) : 512;
    const int t = threadIdx.x;   // 0..1023

    // ---- phase 1: src-side out-degree -> nsrc ----
    if (t < 512) h[t] = 0;
    __syncthreads();
    {
        const int sbeg = counts_s[b * GBIN];
        const int send = (b + 1 < BBUK) ? counts_s[(b + 1) * GBIN] : NE;
        for (int i = sbeg + t; i < send; i += 1024)
            atomicAdd(&h[packed2[i] & 511u], 1);
    }
    __syncthreads();
    if (t < nlim) nsrc[n0 + t] = rsqrtf(fmaxf((float)h[t], 1.0f));
    __syncthreads();

    // ---- phase 2: dst-side CSR build ----
    if (t < 512) h[t] = 0;
    __syncthreads();
    const int beg = counts_d[b * GBIN];
    const int end = (b + 1 < BBUK) ? counts_d[(b + 1) * GBIN] : NE;
    for (int i = beg + t; i < end; i += 1024)
        atomicAdd(&h[packed[i] & 511u], 1);
    __syncthreads();
    const int deg = (t < 512) ? h[t] : 0;          // this thread's node in-degree
    // Blelloch exclusive scan of 512 elems (t<512 active; barriers uniform)
    int offset = 1;
    #pragma unroll
    for (int d = 256; d > 0; d >>= 1) {
        __syncthreads();
        if (t < d) {
            int ai = offset * (2 * t + 1) - 1;
            int bi = offset * (2 * t + 2) - 1;
            h[bi] += h[ai];
        }
        offset <<= 1;
    }
    __syncthreads();
    if (t == 0) h[511] = 0;
    #pragma unroll
    for (int d = 1; d < 512; d <<= 1) {
        offset >>= 1;
        __syncthreads();
        if (t < d) {
            int ai = offset * (2 * t + 1) - 1;
            int bi = offset * (2 * t + 2) - 1;
            int tmp = h[ai]; h[ai] = h[bi]; h[bi] += tmp;
        }
    }
    __syncthreads();
    const int r0 = (t < 512) ? (beg + h[t]) : 0;
    if (t < nlim) {
        row_off[n0 + t] = r0;
        ndst[n0 + t] = rsqrtf(fmaxf((float)deg, 1.0f));
    }
    if (n0 + nlim == NN && t == 0) row_off[NN] = end;
    __syncthreads();
    if (t < 512) h[t] = r0;                        // LDS cursors
    __syncthreads();
    for (int i = beg + t; i < end; i += 1024) {
        unsigned v = packed[i];
        int p = atomicAdd(&h[v & 511u], 1);
        srcs_sorted[p] = (int)(v >> 9);
    }
}

// ---------------- layer 1 GEMM (MFMA, both dtypes) ----------------
__global__ __launch_bounds__(256) void k_gemm1_mfma(
    const void* __restrict__ x, const unsigned short* __restrict__ W1f,
    const float* __restrict__ nsrc, unsigned short* __restrict__ h1,
    const int* __restrict__ mode)
{
    const bool f32 = (mode[0] != 0);
    const int tid = threadIdx.x;
    const int wave = tid >> 6, lane = tid & 63;
    const int col = lane & 15, quad = lane >> 4;

    short8v bfrag[16];
    #pragma unroll
    for (int f = 0; f < 16; ++f)
        bfrag[f] = *(const short8v*)(W1f + ((size_t)f * 64 + lane) * 8);

    const int base = blockIdx.x * 64 + wave * 16;
    int arow = base + col;
    if (arow > NN - 1) arow = NN - 1;

    short8v afrag[4];
    if (f32) {
        const float4* ap = (const float4*)((const float*)x + (size_t)arow * NF);
        #pragma unroll
        for (int kc = 0; kc < 4; ++kc) {
            float4 v0 = ap[kc * 8 + quad * 2];
            float4 v1 = ap[kc * 8 + quad * 2 + 1];
            short8v af;
            af[0] = (short)f2us_rn(v0.x); af[1] = (short)f2us_rn(v0.y);
            af[2] = (short)f2us_rn(v0.z); af[3] = (short)f2us_rn(v0.w);
            af[4] = (short)f2us_rn(v1.x); af[5] = (short)f2us_rn(v1.y);
            af[6] = (short)f2us_rn(v1.z); af[7] = (short)f2us_rn(v1.w);
            afrag[kc] = af;
        }
    } else {
        const uint4* ap = (const uint4*)((const unsigned short*)x + (size_t)arow * NF);
        #pragma unroll
        for (int kc = 0; kc < 4; ++kc) {
            uint4 v = ap[kc * 4 + quad];
            afrag[kc] = *reinterpret_cast<const short8v*>(&v);
        }
    }

    float4v acc[4];
    #pragma unroll
    for (int nt = 0; nt < 4; ++nt) acc[nt] = (float4v){0.f, 0.f, 0.f, 0.f};
    #pragma unroll
    for (int kc = 0; kc < 4; ++kc)
        #pragma unroll
        for (int nt = 0; nt < 4; ++nt)
            acc[nt] = __builtin_amdgcn_mfma_f32_16x16x32_bf16(afrag[kc], bfrag[kc * 4 + nt], acc[nt], 0, 0, 0);

    #pragma unroll
    for (int reg = 0; reg < 4; ++reg) {
        const int row = base + quad * 4 + reg;
        if (row < NN) {
            const float ns = nsrc[row];
            unsigned short* hp = h1 + (size_t)row * NH + col;
            hp[0]  = f2us_rn(acc[0][reg] * ns);
            hp[16] = f2us_rn(acc[1][reg] * ns);
            hp[32] = f2us_rn(acc[2][reg] * ns);
            hp[48] = f2us_rn(acc[3][reg] * ns);
        }
    }
}

// ---------------- fused layer-1 aggregation + relu + W2 GEMM ----------------
// R12 body - FROZEN. History: R11 wider slots 70us, R13 two-row 71us, R14
// gload_lds prefetch 98us, R17 bucket-LDS 700us - all reverted. 60us = this
// gather structure's floor: 89MB L2-miss traffic (mostly L3-hit) at 1.46 TB/s,
// MSHR/concurrency bound; more per-wave MLP only lengthens in-order vmcnt
// drain chains.
__global__ __launch_bounds__(256) void k_agg1csr(
    const int* __restrict__ row_off, const int* __restrict__ srcs,
    const unsigned short* __restrict__ h1, const float* __restrict__ ndst,
    const float* __restrict__ nsrc, const void* __restrict__ b1,
    const void* __restrict__ W2, const int* __restrict__ mode,
    unsigned short* __restrict__ h2)
{
    const bool f32 = (mode[0] != 0);
    const int lane = threadIdx.x & 63;
    const int q  = lane >> 4;    // edge slot / column subset
    const int li = lane & 15;    // feature quad: feats 4li..4li+3

    const float bias0 = ldf(b1, 4*li+0, f32), bias1 = ldf(b1, 4*li+1, f32);
    const float bias2 = ldf(b1, 4*li+2, f32), bias3 = ldf(b1, 4*li+3, f32);
    float w2[4][4];
    #pragma unroll
    for (int j = 0; j < 4; ++j)
        #pragma unroll
        for (int m = 0; m < 4; ++m)
            w2[j][m] = ldf(W2, (size_t)(4*li+j)*NC + (q + 4*m), f32);

    const int wid = (blockIdx.x * blockDim.x + threadIdx.x) >> 6;
    const int nw  = (gridDim.x * blockDim.x) >> 6;
    const uint2* __restrict__ h1v = (const uint2*)h1;
    const unsigned uli = (unsigned)li;

    int row = wid;
    if (row >= NN) return;
    int beg = row_off[row];
    int end = row_off[row + 1];
    float nd = ndst[row];
    float ns = nsrc[row];

    while (row < NN) {
        // prefetch next row's descriptors; in flight during this row's gathers
        const int nrow = row + nw;
        int nbeg = 0, nend = 0;
        float nnd = 0.f, nns = 0.f;
        if (nrow < NN) {
            nbeg = row_off[nrow];
            nend = row_off[nrow + 1];
            nnd  = ndst[nrow];
            nns  = nsrc[nrow];
        }

        float ax = 0.f, ay = 0.f, az = 0.f, aw = 0.f;
        float bx = 0.f, by = 0.f, bz = 0.f, bw = 0.f;
        const int e1 = end - 1;
        int i = beg + q;
        while (i < end) {
            const int j1 = i + 4, j2 = i + 8, j3 = i + 12;
            const int t1 = (j1 < end) ? j1 : e1;
            const int t2 = (j2 < end) ? j2 : e1;
            const int t3 = (j3 < end) ? j3 : e1;
            const int s0 = srcs[(unsigned)i];
            const int s1 = srcs[(unsigned)t1];
            const int s2 = srcs[(unsigned)t2];
            const int s3 = srcs[(unsigned)t3];
            const uint2 v0 = h1v[(unsigned)s0 * 16u + uli];
            const uint2 v1 = h1v[(unsigned)s1 * 16u + uli];
            const uint2 v2 = h1v[(unsigned)s2 * 16u + uli];
            const uint2 v3 = h1v[(unsigned)s3 * 16u + uli];
            ax += bflo(v0.x); ay += bfhi(v0.x);
            az += bflo(v0.y); aw += bfhi(v0.y);
            if (j1 < end) {
                bx += bflo(v1.x); by += bfhi(v1.x);
                bz += bflo(v1.y); bw += bfhi(v1.y);
            }
            if (j2 < end) {
                ax += bflo(v2.x); ay += bfhi(v2.x);
                az += bflo(v2.y); aw += bfhi(v2.y);
            }
            if (j3 < end) {
                bx += bflo(v3.x); by += bfhi(v3.x);
                bz += bflo(v3.y); bw += bfhi(v3.y);
            }
            i += 16;
        }
        ax += bx; ay += by; az += bz; aw += bw;
        ax += __shfl_xor(ax, 16); ay += __shfl_xor(ay, 16);
        az += __shfl_xor(az, 16); aw += __shfl_xor(aw, 16);
        ax += __shfl_xor(ax, 32); ay += __shfl_xor(ay, 32);
        az += __shfl_xor(az, 32); aw += __shfl_xor(aw, 32);

        const float t0 = fmaxf(fmaf(ax, nd, bias0), 0.f);
        const float t1f = fmaxf(fmaf(ay, nd, bias1), 0.f);
        const float t2f = fmaxf(fmaf(az, nd, bias2), 0.f);
        const float t3f = fmaxf(fmaf(aw, nd, bias3), 0.f);

        float p0 = fmaf(t0,w2[0][0],fmaf(t1f,w2[1][0],fmaf(t2f,w2[2][0],t3f*w2[3][0])));
        float p1 = fmaf(t0,w2[0][1],fmaf(t1f,w2[1][1],fmaf(t2f,w2[2][1],t3f*w2[3][1])));
        float p2 = fmaf(t0,w2[0][2],fmaf(t1f,w2[1][2],fmaf(t2f,w2[2][2],t3f*w2[3][2])));
        float p3 = fmaf(t0,w2[0][3],fmaf(t1f,w2[1][3],fmaf(t2f,w2[2][3],t3f*w2[3][3])));
        #pragma unroll
        for (int off = 1; off <= 8; off <<= 1) {
            p0 += __shfl_xor(p0, off);
            p1 += __shfl_xor(p1, off);
            p2 += __shfl_xor(p2, off);
            p3 += __shfl_xor(p3, off);
        }
        if (li < 4) {
            float v = (li == 0) ? p0 : (li == 1) ? p1 : (li == 2) ? p2 : p3;
            h2[(size_t)row * NC + q + 4*li] = f2us_rn(v * ns);
        }

        row = nrow; beg = nbeg; end = nend; nd = nnd; ns = nns;
    }
}

// ---------------- fused layer-2 aggregation + bias + log_softmax ----------------
// R12 form (h2 is 3.2MB -> per-XCD-L2 resident; gathers mostly L2 hits).
__global__ __launch_bounds__(256) void k_out(
    const int* __restrict__ row_off, const int* __restrict__ srcs,
    const unsigned short* __restrict__ h2, const float* __restrict__ ndst,
    const void* __restrict__ b2, const int* __restrict__ mode,
    void* __restrict__ out)
{
    const bool f32 = (mode[0] != 0);
    const int lane = threadIdx.x & 63;
    const int q  = lane >> 3;
    const int li = lane & 7;
    const float b2v0 = ldf(b2, 2*li,   f32);
    const float b2v1 = ldf(b2, 2*li+1, f32);

    const int wid = (blockIdx.x * blockDim.x + threadIdx.x) >> 6;
    const int nw  = (gridDim.x * blockDim.x) >> 6;
    const unsigned* __restrict__ h2v = (const unsigned*)h2;
    const unsigned uli = (unsigned)li;

    int row = wid;
    if (row >= NN) return;
    int beg = row_off[row];
    int end = row_off[row + 1];
    float nd = ndst[row];

    while (row < NN) {
        const int nrow = row + nw;
        int nbeg = 0, nend = 0;
        float nnd = 0.f;
        if (nrow < NN) {
            nbeg = row_off[nrow];
            nend = row_off[nrow + 1];
            nnd  = ndst[nrow];
        }

        float a0 = 0.f, a1 = 0.f, c0 = 0.f, c1 = 0.f;
        const int e1 = end - 1;
        int i = beg + q;
        while (i < end) {
            const int j1 = i + 8;
            const int t1 = (j1 < end) ? j1 : e1;
            const int s0 = srcs[(unsigned)i];
            const int s1 = srcs[(unsigned)t1];
            const unsigned u0 = h2v[(unsigned)s0 * 8u + uli];
            const unsigned u1 = h2v[(unsigned)s1 * 8u + uli];
            a0 += bflo(u0); a1 += bfhi(u0);
            if (j1 < end) {
                c0 += bflo(u1); c1 += bfhi(u1);
            }
            i += 16;
        }
        a0 += c0; a1 += c1;
        #pragma unroll
        for (int off = 8; off <= 32; off <<= 1) {
            a0 += __shfl_xor(a0, off);
            a1 += __shfl_xor(a1, off);
        }
        float v0 = fmaf(a0, nd, b2v0);
        float v1 = fmaf(a1, nd, b2v1);
        float m = fmaxf(v0, v1);
        #pragma unroll
        for (int off = 1; off <= 4; off <<= 1) m = fmaxf(m, __shfl_xor(m, off));
        float sm = __expf(v0 - m) + __expf(v1 - m);
        #pragma unroll
        for (int off = 1; off <= 4; off <<= 1) sm += __shfl_xor(sm, off);
        const float lsm = __logf(sm);
        const float r0 = v0 - m - lsm, r1 = v1 - m - lsm;
        if (q == 0) {
            if (f32) {
                float2 o; o.x = r0; o.y = r1;
                *(float2*)((float*)out + (size_t)row * NC + 2*li) = o;
            } else {
                unsigned o = ((unsigned)f2us_rn(r1) << 16) | (unsigned)f2us_rn(r0);
                *(unsigned*)((unsigned short*)out + (size_t)row * NC + 2*li) = o;
            }
        }

        row = nrow; beg = nbeg; end = nend; nd = nnd;
    }
}

extern "C" void kernel_launch(void* const* d_in, const int* in_sizes, int n_in,
                              void* d_out, int out_size, void* d_ws, size_t ws_size,
                              hipStream_t stream) {
    const void* x  = d_in[0];
    const int* src = (const int*)d_in[1];
    const int* dst = (const int*)d_in[2];
    const void* W1 = d_in[3];
    const void* b1 = d_in[4];
    const void* W2 = d_in[5];
    const void* b2 = d_in[6];

    // ---- workspace layout (R1-identical) ----
    char* ws = (char*)d_ws;
    const size_t O_MODE = 0;                     // 1 KB
    const size_t O_W1F  = 1024;                  // fragment-ordered W1 (bf16), 16384 B
    const size_t O_CNT  = O_W1F + 16384;         // counts_d + counts_s = 401408
    const size_t O_CS   = O_CNT  + 401408;       // csum 2048 + coff 2048
    const size_t O_DEG  = O_CS   + 4096;         // 800000 (fallback only)
    const size_t O_NSRC = O_DEG  + 800000;
    const size_t O_NDST = O_NSRC + 400000;
    const size_t O_ROW  = O_NDST + 400000;       // (NN+1)*4 padded
    const size_t O_CUR  = O_ROW  + 400128;       // fallback per-node cursors
    const size_t O_BS   = O_CUR  + 400128;       // bsum 2048 + boff 2048 (fallback)
    const size_t O_SRCS = O_BS   + 4096;         // NE*4
    const size_t O_H2   = O_SRCS + 6400000;      // NN*NC*2 bf16
    const size_t O_H1   = O_H2   + 3200000;      // NN*NH*2 bf16 = 12800000
    // packed (NE*4) + packed2 (NE*2) alias into h1 (dead before gemm1)
    const size_t NEED = O_H1 + 12800000;         // ~25.2 MB
    const bool fast_csr = ws_size >= NEED;

    int*   mode     = (int*)(ws + O_MODE);
    unsigned short* W1f = (unsigned short*)(ws + O_W1F);
    int*   counts_d = (int*)(ws + O_CNT);
    int*   counts_s = counts_d + BBUK * GBIN;
    int*   csum     = (int*)(ws + O_CS);
    int*   coff     = (int*)(ws + O_CS + 2048);
    int*   deg_out  = (int*)(ws + O_DEG);
    int*   deg_in   = deg_out + NN;
    float* nsrc     = (float*)(ws + O_NSRC);
    float* ndst     = (float*)(ws + O_NDST);
    int*   row_off  = (int*)(ws + O_ROW);
    int*   cursor   = (int*)(ws + O_CUR);
    int*   bsum     = (int*)(ws + O_BS);
    int*   boff     = (int*)(ws + O_BS + 2048);
    int*   srcs_s   = (int*)(ws + O_SRCS);
    unsigned short* h2 = (unsigned short*)(ws + O_H2);
    unsigned short* h1 = (unsigned short*)(ws + O_H1);
    unsigned int*   packed  = (unsigned int*)(ws + O_H1);
    unsigned short* packed2 = (unsigned short*)(ws + O_H1 + 6400000);

    if (fast_csr) {
        k_hist2s<<<GBIN + 1, 1024, 0, stream>>>(src, dst, counts_d, counts_s,
                                                (const unsigned short*)x, W1, W1f, mode);
        k_cs_a<<<2 * NCB, 256, 0, stream>>>(counts_d, csum);
        k_cs_c<<<2 * NCB, 256, 0, stream>>>(counts_d, csum);
        k_binscatter2<<<GBIN, 1024, 0, stream>>>(src, dst, counts_d, counts_s, packed, packed2);
        k_bucket2<<<BBUK, 1024, 0, stream>>>(counts_d, counts_s, packed, packed2,
                                             row_off, ndst, nsrc, srcs_s);
    } else {
        k_sniffprep<<<1, 256, 0, stream>>>((const unsigned short*)x, W1, W1f, mode);
        hipMemsetAsync(deg_out, 0, 2 * (size_t)NN * sizeof(int), stream);
        k_deg<<<(NE / 4 + 255) / 256, 256, 0, stream>>>((const int4*)src, (const int4*)dst, deg_out, deg_in);
        k_scan_a<<<NB1, 256, 0, stream>>>(deg_in, bsum);
        k_scan_b<<<1, 512, 0, stream>>>(bsum, boff);
        k_scan_c<<<NB1, 256, 0, stream>>>(deg_in, deg_out, boff, row_off, cursor, nsrc, ndst);
        k_scatter<<<(NE + 255) / 256, 256, 0, stream>>>(src, dst, cursor, srcs_s);
    }
    k_gemm1_mfma<<<NGRP, 256, 0, stream>>>(x, W1f, nsrc, h1, mode);
    k_agg1csr<<<2048, 256, 0, stream>>>(row_off, srcs_s, h1, ndst, nsrc, b1, W2, mode, h2);
    k_out<<<2048, 256, 0, stream>>>(row_off, srcs_s, h2, ndst, b2, mode, d_out);
}

// Round 11
// 234.697 us; speedup vs baseline: 4.4513x; 1.0053x over previous
//
#include <hip/hip_runtime.h>
#include <hip/hip_bf16.h>

#define NN 100000
#define NE 1600000
#define NF 128
#define NH 64
#define NC 16
#define NB1 391    // ceil(NN/256)
#define GBIN 256   // binning workgroups
#define CHUNK 6250 // NE/GBIN
#define BBUK 196   // ceil(NN/512) coarse buckets of 512 nodes
#define NCB 196    // 256-blocks per counts array (BBUK*GBIN/256)
#define NGRP 1563  // ceil(NN/64) gemm1 row-groups

typedef __attribute__((ext_vector_type(8))) short short8v;
typedef __attribute__((ext_vector_type(4))) float float4v;

__device__ __forceinline__ float us2f(unsigned short u) {
    return __uint_as_float(((unsigned int)u) << 16);
}
__device__ __forceinline__ float bflo(unsigned u) {   // low bf16 of a packed pair
    return __uint_as_float(u << 16);
}
__device__ __forceinline__ float bfhi(unsigned u) {   // high bf16 of a packed pair
    return __uint_as_float(u & 0xFFFF0000u);
}
__device__ __forceinline__ unsigned short f2us_rn(float f) {
    unsigned int u = __float_as_uint(f);
    return (unsigned short)((u + 0x7FFFu + ((u >> 16) & 1u)) >> 16);
}
__device__ __forceinline__ float ldf(const void* p, size_t i, bool f32) {
    return f32 ? ((const float*)p)[i] : us2f(((const unsigned short*)p)[i]);
}

// ---------------- standalone sniff+prep (FALLBACK path only) ----------------
__global__ void k_sniffprep(const unsigned short* __restrict__ xu,
                            const void* __restrict__ W1,
                            unsigned short* __restrict__ W1f,
                            int* __restrict__ mode) {
    __shared__ int cnt;
    if (threadIdx.x == 0) cnt = 0;
    __syncthreads();
    int c = 0;
    for (int i = threadIdx.x; i < 4096; i += 256) {
        unsigned int e = (xu[i] >> 7) & 0xFFu;
        if (e >= 160u) c++;
    }
    atomicAdd(&cnt, c);
    __syncthreads();
    if (threadIdx.x == 0) mode[0] = (cnt >= 16) ? 1 : 0;
    __syncthreads();
    const bool f32 = (cnt >= 16);
    for (int i = threadIdx.x; i < 1024; i += 256) {
        const int kcnt = i >> 6, lane = i & 63;
        const int kc = kcnt >> 2, nt = kcnt & 3;
        const int quad = lane >> 4, col = lane & 15;
        #pragma unroll
        for (int j = 0; j < 8; ++j) {
            const size_t idx = (size_t)(kc * 32 + quad * 8 + j) * NH + nt * 16 + col;
            W1f[(size_t)i * 8 + j] = f32 ? f2us_rn(((const float*)W1)[idx])
                                         : ((const unsigned short*)W1)[idx];
        }
    }
}

// ---------------- fallback path kernels (global atomics) ----------------
__global__ void k_deg(const int4* __restrict__ src4, const int4* __restrict__ dst4,
                      int* __restrict__ deg_out, int* __restrict__ deg_in) {
    int i = blockIdx.x * blockDim.x + threadIdx.x;
    if (i < NE / 4) {
        int4 s = src4[i], d = dst4[i];
        atomicAdd(&deg_out[s.x], 1); atomicAdd(&deg_out[s.y], 1);
        atomicAdd(&deg_out[s.z], 1); atomicAdd(&deg_out[s.w], 1);
        atomicAdd(&deg_in[d.x], 1);  atomicAdd(&deg_in[d.y], 1);
        atomicAdd(&deg_in[d.z], 1);  atomicAdd(&deg_in[d.w], 1);
    }
}

__global__ void k_scatter(const int* __restrict__ src, const int* __restrict__ dst,
                          int* __restrict__ cursor, int* __restrict__ srcs_sorted) {
    int e = blockIdx.x * blockDim.x + threadIdx.x;
    if (e < NE) {
        int p = atomicAdd(&cursor[dst[e]], 1);
        srcs_sorted[p] = src[e];
    }
}

__global__ void k_scan_a(const int* __restrict__ deg_in, int* __restrict__ bsum) {
    __shared__ int s[256];
    int i = blockIdx.x * 256 + threadIdx.x;
    s[threadIdx.x] = (i < NN) ? deg_in[i] : 0;
    __syncthreads();
    for (int off = 128; off > 0; off >>= 1) {
        if (threadIdx.x < off) s[threadIdx.x] += s[threadIdx.x + off];
        __syncthreads();
    }
    if (threadIdx.x == 0) bsum[blockIdx.x] = s[0];
}

__global__ void k_scan_b(const int* __restrict__ bsum, int* __restrict__ boff) {
    __shared__ int s[512];
    int t = threadIdx.x;
    s[t] = (t < NB1) ? bsum[t] : 0;
    __syncthreads();
    for (int off = 1; off < 512; off <<= 1) {
        int v = (t >= off) ? s[t - off] : 0;
        __syncthreads();
        s[t] += v;
        __syncthreads();
    }
    if (t < NB1) boff[t] = (t == 0) ? 0 : s[t - 1];
}

__global__ void k_scan_c(const int* __restrict__ deg_in, const int* __restrict__ deg_out,
                         const int* __restrict__ boff, int* __restrict__ row_off,
                         int* __restrict__ cursor, float* __restrict__ nsrc,
                         float* __restrict__ ndst) {
    __shared__ int s[256];
    int t = threadIdx.x;
    int i = blockIdx.x * 256 + t;
    int d = (i < NN) ? deg_in[i] : 0;
    s[t] = d;
    __syncthreads();
    for (int off = 1; off < 256; off <<= 1) {
        int v = (t >= off) ? s[t - off] : 0;
        __syncthreads();
        s[t] += v;
        __syncthreads();
    }
    int excl = s[t] - d + boff[blockIdx.x];
    if (i < NN) {
        row_off[i] = excl;
        cursor[i]  = excl;
        ndst[i] = rsqrtf(fmaxf((float)d, 1.0f));
        nsrc[i] = rsqrtf(fmaxf((float)deg_out[i], 1.0f));
        if (i == NN - 1) row_off[NN] = excl + d;
    }
}

// ---------------- R20 fast CSR 1: histograms @1024 threads + fused sniff/prep block ----------------
// R19: 256->512 threads was +; R21: 512->1024 (+8us). These ~256-block kernels
// run ~1 block/CU, so block size IS the wave-occupancy lever.
__global__ __launch_bounds__(1024) void k_hist2s(const int* __restrict__ src,
                                                 const int* __restrict__ dst,
                                                 int* __restrict__ counts_d,
                                                 int* __restrict__ counts_s,
                                                 const unsigned short* __restrict__ xu,
                                                 const void* __restrict__ W1,
                                                 unsigned short* __restrict__ W1f,
                                                 int* __restrict__ mode) {
    __shared__ int hd[BBUK], hs[BBUK];
    __shared__ int cnt;
    const int t = threadIdx.x;
    if (blockIdx.x == GBIN) {
        // ---- sniff + W1 fragment repack ----
        if (t == 0) cnt = 0;
        __syncthreads();
        int c = 0;
        for (int i = t; i < 4096; i += 1024) {
            unsigned int e = (xu[i] >> 7) & 0xFFu;
            if (e >= 160u) c++;
        }
        atomicAdd(&cnt, c);
        __syncthreads();
        if (t == 0) mode[0] = (cnt >= 16) ? 1 : 0;
        __syncthreads();
        const bool f32 = (cnt >= 16);
        for (int i = t; i < 1024; i += 1024) {
            const int kcnt = i >> 6, lane = i & 63;
            const int kc = kcnt >> 2, nt = kcnt & 3;
            const int quad = lane >> 4, col = lane & 15;
            #pragma unroll
            for (int j = 0; j < 8; ++j) {
                const size_t idx = (size_t)(kc * 32 + quad * 8 + j) * NH + nt * 16 + col;
                W1f[(size_t)i * 8 + j] = f32 ? f2us_rn(((const float*)W1)[idx])
                                             : ((const unsigned short*)W1)[idx];
            }
        }
        return;
    }
    // ---- per-(bucket,group) histograms ----
    for (int i = t; i < BBUK; i += 1024) { hd[i] = 0; hs[i] = 0; }
    __syncthreads();
    const int g = blockIdx.x;
    const int e0 = g * CHUNK;
    for (int i = t; i < CHUNK; i += 1024) {
        atomicAdd(&hd[dst[e0 + i] >> 9], 1);
        atomicAdd(&hs[src[e0 + i] >> 9], 1);
    }
    __syncthreads();
    for (int i = t; i < BBUK; i += 1024) {
        counts_d[i * GBIN + g] = hd[i];
        counts_s[i * GBIN + g] = hs[i];
    }
}

// ---------------- fast CSR 2a: per-256-block sums ----------------
__global__ void k_cs_a(const int* __restrict__ counts, int* __restrict__ csum) {
    __shared__ int s[256];
    int i = blockIdx.x * 256 + threadIdx.x;
    s[threadIdx.x] = counts[i];
    __syncthreads();
    for (int off = 128; off > 0; off >>= 1) {
        if (threadIdx.x < off) s[threadIdx.x] += s[threadIdx.x + off];
        __syncthreads();
    }
    if (threadIdx.x == 0) csum[blockIdx.x] = s[0];
}

// ---------------- R19 fast CSR 2b: intra-block scan with SELF-COMPUTED offset ----------------
__global__ void k_cs_c(int* __restrict__ counts, const int* __restrict__ csum) {
    __shared__ int s[256];
    const int t = threadIdx.x;
    const int blk = blockIdx.x;                 // 0..2*NCB-1
    const int half = (blk >= NCB) ? 1 : 0;
    const int j = blk - half * NCB;             // block index within its half
    s[t] = (t < j) ? csum[half * NCB + t] : 0;
    __syncthreads();
    for (int off = 128; off > 0; off >>= 1) {
        if (t < off) s[t] += s[t + off];
        __syncthreads();
    }
    const int blockoff = s[0];
    __syncthreads();
    const int i = blk * 256 + t;
    const int v = counts[i];
    s[t] = v;
    __syncthreads();
    for (int off = 1; off < 256; off <<= 1) {
        int u = (t >= off) ? s[t - off] : 0;
        __syncthreads();
        s[t] += u;
        __syncthreads();
    }
    counts[i] = s[t] - v + blockoff;
}

// ---------------- R20 fast CSR 3: private-slice binning @1024 threads ----------------
__global__ __launch_bounds__(1024) void k_binscatter2(const int* __restrict__ src,
                                                      const int* __restrict__ dst,
                                                      const int* __restrict__ counts_d,
                                                      const int* __restrict__ counts_s,
                                                      unsigned int* __restrict__ packed,
                                                      unsigned short* __restrict__ packed2) {
    __shared__ int curd[BBUK], curs[BBUK];
    const int t = threadIdx.x;
    const int g = blockIdx.x;
    for (int i = t; i < BBUK; i += 1024) {
        curd[i] = counts_d[i * GBIN + g];
        curs[i] = counts_s[i * GBIN + g];
    }
    __syncthreads();
    const int e0 = g * CHUNK;
    for (int i = t; i < CHUNK; i += 1024) {
        int s = src[e0 + i], d = dst[e0 + i];
        int pd = atomicAdd(&curd[d >> 9], 1);
        packed[pd] = ((unsigned)s << 9) | (unsigned)(d & 511);
        int ps = atomicAdd(&curs[s >> 9], 1);
        packed2[ps] = (unsigned short)(s & 511);
    }
}

// ---------------- R20 fast CSR 4+5 fused, @1024 threads ----------------
// Scan section stays 512-wide (t<512 guards, uniform barriers); the atomic
// histogram / scatter loops use all 16 waves.
__global__ __launch_bounds__(1024) void k_bucket2(const int* __restrict__ counts_d,
                                                  const int* __restrict__ counts_s,
                                                  const unsigned int* __restrict__ packed,
                                                  const unsigned short* __restrict__ packed2,
                                                  int* __restrict__ row_off,
                                                  float* __restrict__ ndst,
                                                  float* __restrict__ nsrc,
                                                  int* __restrict__ srcs_sorted) {
    __shared__ int h[512];
    const int b = blockIdx.x;
    const int n0 = b << 9;
    const int nlim = (NN - n0 < 512) ? (NN - n0) : 512;
    const int t = threadIdx.x;   // 0..1023

    // ---- phase 1: src-side out-degree -> nsrc ----
    if (t < 512) h[t] = 0;
    __syncthreads();
    {
        const int sbeg = counts_s[b * GBIN];
        const int send = (b + 1 < BBUK) ? counts_s[(b + 1) * GBIN] : NE;
        for (int i = sbeg + t; i < send; i += 1024)
            atomicAdd(&h[packed2[i] & 511u], 1);
    }
    __syncthreads();
    if (t < nlim) nsrc[n0 + t] = rsqrtf(fmaxf((float)h[t], 1.0f));
    __syncthreads();

    // ---- phase 2: dst-side CSR build ----
    if (t < 512) h[t] = 0;
    __syncthreads();
    const int beg = counts_d[b * GBIN];
    const int end = (b + 1 < BBUK) ? counts_d[(b + 1) * GBIN] : NE;
    for (int i = beg + t; i < end; i += 1024)
        atomicAdd(&h[packed[i] & 511u], 1);
    __syncthreads();
    const int deg = (t < 512) ? h[t] : 0;          // this thread's node in-degree
    // Blelloch exclusive scan of 512 elems (t<512 active; barriers uniform)
    int offset = 1;
    #pragma unroll
    for (int d = 256; d > 0; d >>= 1) {
        __syncthreads();
        if (t < d) {
            int ai = offset * (2 * t + 1) - 1;
            int bi = offset * (2 * t + 2) - 1;
            h[bi] += h[ai];
        }
        offset <<= 1;
    }
    __syncthreads();
    if (t == 0) h[511] = 0;
    #pragma unroll
    for (int d = 1; d < 512; d <<= 1) {
        offset >>= 1;
        __syncthreads();
        if (t < d) {
            int ai = offset * (2 * t + 1) - 1;
            int bi = offset * (2 * t + 2) - 1;
            int tmp = h[ai]; h[ai] = h[bi]; h[bi] += tmp;
        }
    }
    __syncthreads();
    const int r0 = (t < 512) ? (beg + h[t]) : 0;
    if (t < nlim) {
        row_off[n0 + t] = r0;
        ndst[n0 + t] = rsqrtf(fmaxf((float)deg, 1.0f));
    }
    if (n0 + nlim == NN && t == 0) row_off[NN] = end;
    __syncthreads();
    if (t < 512) h[t] = r0;                        // LDS cursors
    __syncthreads();
    for (int i = beg + t; i < end; i += 1024) {
        unsigned v = packed[i];
        int p = atomicAdd(&h[v & 511u], 1);
        srcs_sorted[p] = (int)(v >> 9);
    }
}

// ---------------- layer 1 GEMM (MFMA, both dtypes) ----------------
__global__ __launch_bounds__(256) void k_gemm1_mfma(
    const void* __restrict__ x, const unsigned short* __restrict__ W1f,
    const float* __restrict__ nsrc, unsigned short* __restrict__ h1,
    const int* __restrict__ mode)
{
    const bool f32 = (mode[0] != 0);
    const int tid = threadIdx.x;
    const int wave = tid >> 6, lane = tid & 63;
    const int col = lane & 15, quad = lane >> 4;

    short8v bfrag[16];
    #pragma unroll
    for (int f = 0; f < 16; ++f)
        bfrag[f] = *(const short8v*)(W1f + ((size_t)f * 64 + lane) * 8);

    const int base = blockIdx.x * 64 + wave * 16;
    int arow = base + col;
    if (arow > NN - 1) arow = NN - 1;

    short8v afrag[4];
    if (f32) {
        const float4* ap = (const float4*)((const float*)x + (size_t)arow * NF);
        #pragma unroll
        for (int kc = 0; kc < 4; ++kc) {
            float4 v0 = ap[kc * 8 + quad * 2];
            float4 v1 = ap[kc * 8 + quad * 2 + 1];
            short8v af;
            af[0] = (short)f2us_rn(v0.x); af[1] = (short)f2us_rn(v0.y);
            af[2] = (short)f2us_rn(v0.z); af[3] = (short)f2us_rn(v0.w);
            af[4] = (short)f2us_rn(v1.x); af[5] = (short)f2us_rn(v1.y);
            af[6] = (short)f2us_rn(v1.z); af[7] = (short)f2us_rn(v1.w);
            afrag[kc] = af;
        }
    } else {
        const uint4* ap = (const uint4*)((const unsigned short*)x + (size_t)arow * NF);
        #pragma unroll
        for (int kc = 0; kc < 4; ++kc) {
            uint4 v = ap[kc * 4 + quad];
            afrag[kc] = *reinterpret_cast<const short8v*>(&v);
        }
    }

    float4v acc[4];
    #pragma unroll
    for (int nt = 0; nt < 4; ++nt) acc[nt] = (float4v){0.f, 0.f, 0.f, 0.f};
    #pragma unroll
    for (int kc = 0; kc < 4; ++kc)
        #pragma unroll
        for (int nt = 0; nt < 4; ++nt)
            acc[nt] = __builtin_amdgcn_mfma_f32_16x16x32_bf16(afrag[kc], bfrag[kc * 4 + nt], acc[nt], 0, 0, 0);

    #pragma unroll
    for (int reg = 0; reg < 4; ++reg) {
        const int row = base + quad * 4 + reg;
        if (row < NN) {
            const float ns = nsrc[row];
            unsigned short* hp = h1 + (size_t)row * NH + col;
            hp[0]  = f2us_rn(acc[0][reg] * ns);
            hp[16] = f2us_rn(acc[1][reg] * ns);
            hp[32] = f2us_rn(acc[2][reg] * ns);
            hp[48] = f2us_rn(acc[3][reg] * ns);
        }
    }
}

// ---------------- fused layer-1 aggregation + relu + W2 GEMM ----------------
// R12 body - FROZEN. History: R11 wider slots 70us, R13 two-row 71us, R14
// gload_lds prefetch 98us, R17 bucket-LDS 700us - all reverted. 60us = this
// gather structure's floor: 89MB L2-miss traffic (mostly L3-hit) at 1.46 TB/s,
// MSHR/concurrency bound; more per-wave MLP only lengthens in-order vmcnt
// drain chains.
__global__ __launch_bounds__(256) void k_agg1csr(
    const int* __restrict__ row_off, const int* __restrict__ srcs,
    const unsigned short* __restrict__ h1, const float* __restrict__ ndst,
    const float* __restrict__ nsrc, const void* __restrict__ b1,
    const void* __restrict__ W2, const int* __restrict__ mode,
    unsigned short* __restrict__ h2)
{
    const bool f32 = (mode[0] != 0);
    const int lane = threadIdx.x & 63;
    const int q  = lane >> 4;    // edge slot / column subset
    const int li = lane & 15;    // feature quad: feats 4li..4li+3

    const float bias0 = ldf(b1, 4*li+0, f32), bias1 = ldf(b1, 4*li+1, f32);
    const float bias2 = ldf(b1, 4*li+2, f32), bias3 = ldf(b1, 4*li+3, f32);
    float w2[4][4];
    #pragma unroll
    for (int j = 0; j < 4; ++j)
        #pragma unroll
        for (int m = 0; m < 4; ++m)
            w2[j][m] = ldf(W2, (size_t)(4*li+j)*NC + (q + 4*m), f32);

    const int wid = (blockIdx.x * blockDim.x + threadIdx.x) >> 6;
    const int nw  = (gridDim.x * blockDim.x) >> 6;
    const uint2* __restrict__ h1v = (const uint2*)h1;
    const unsigned uli = (unsigned)li;

    int row = wid;
    if (row >= NN) return;
    int beg = row_off[row];
    int end = row_off[row + 1];
    float nd = ndst[row];
    float ns = nsrc[row];

    while (row < NN) {
        // prefetch next row's descriptors; in flight during this row's gathers
        const int nrow = row + nw;
        int nbeg = 0, nend = 0;
        float nnd = 0.f, nns = 0.f;
        if (nrow < NN) {
            nbeg = row_off[nrow];
            nend = row_off[nrow + 1];
            nnd  = ndst[nrow];
            nns  = nsrc[nrow];
        }

        float ax = 0.f, ay = 0.f, az = 0.f, aw = 0.f;
        float bx = 0.f, by = 0.f, bz = 0.f, bw = 0.f;
        const int e1 = end - 1;
        int i = beg + q;
        while (i < end) {
            const int j1 = i + 4, j2 = i + 8, j3 = i + 12;
            const int t1 = (j1 < end) ? j1 : e1;
            const int t2 = (j2 < end) ? j2 : e1;
            const int t3 = (j3 < end) ? j3 : e1;
            const int s0 = srcs[(unsigned)i];
            const int s1 = srcs[(unsigned)t1];
            const int s2 = srcs[(unsigned)t2];
            const int s3 = srcs[(unsigned)t3];
            const uint2 v0 = h1v[(unsigned)s0 * 16u + uli];
            const uint2 v1 = h1v[(unsigned)s1 * 16u + uli];
            const uint2 v2 = h1v[(unsigned)s2 * 16u + uli];
            const uint2 v3 = h1v[(unsigned)s3 * 16u + uli];
            ax += bflo(v0.x); ay += bfhi(v0.x);
            az += bflo(v0.y); aw += bfhi(v0.y);
            if (j1 < end) {
                bx += bflo(v1.x); by += bfhi(v1.x);
                bz += bflo(v1.y); bw += bfhi(v1.y);
            }
            if (j2 < end) {
                ax += bflo(v2.x); ay += bfhi(v2.x);
                az += bflo(v2.y); aw += bfhi(v2.y);
            }
            if (j3 < end) {
                bx += bflo(v3.x); by += bfhi(v3.x);
                bz += bflo(v3.y); bw += bfhi(v3.y);
            }
            i += 16;
        }
        ax += bx; ay += by; az += bz; aw += bw;
        ax += __shfl_xor(ax, 16); ay += __shfl_xor(ay, 16);
        az += __shfl_xor(az, 16); aw += __shfl_xor(aw, 16);
        ax += __shfl_xor(ax, 32); ay += __shfl_xor(ay, 32);
        az += __shfl_xor(az, 32); aw += __shfl_xor(aw, 32);

        const float t0 = fmaxf(fmaf(ax, nd, bias0), 0.f);
        const float t1f = fmaxf(fmaf(ay, nd, bias1), 0.f);
        const float t2f = fmaxf(fmaf(az, nd, bias2), 0.f);
        const float t3f = fmaxf(fmaf(aw, nd, bias3), 0.f);

        float p0 = fmaf(t0,w2[0][0],fmaf(t1f,w2[1][0],fmaf(t2f,w2[2][0],t3f*w2[3][0])));
        float p1 = fmaf(t0,w2[0][1],fmaf(t1f,w2[1][1],fmaf(t2f,w2[2][1],t3f*w2[3][1])));
        float p2 = fmaf(t0,w2[0][2],fmaf(t1f,w2[1][2],fmaf(t2f,w2[2][2],t3f*w2[3][2])));
        float p3 = fmaf(t0,w2[0][3],fmaf(t1f,w2[1][3],fmaf(t2f,w2[2][3],t3f*w2[3][3])));
        #pragma unroll
        for (int off = 1; off <= 8; off <<= 1) {
            p0 += __shfl_xor(p0, off);
            p1 += __shfl_xor(p1, off);
            p2 += __shfl_xor(p2, off);
            p3 += __shfl_xor(p3, off);
        }
        if (li < 4) {
            float v = (li == 0) ? p0 : (li == 1) ? p1 : (li == 2) ? p2 : p3;
            h2[(size_t)row * NC + q + 4*li] = f2us_rn(v * ns);
        }

        row = nrow; beg = nbeg; end = nend; nd = nnd; ns = nns;
    }
}

// ---------------- fused layer-2 aggregation + bias + log_softmax ----------------
// R22: 4-deep edge pipeline (R12 analog). Rationale: h2 = 3.2MB fits the 4MiB
// per-XCD L2 -> gathers are ~200cy L2 hits (vs agg1's ~900cy L3), so k_out is
// near the ISSUE-limited regime where fewer trips + more in-flight loads pay
// (R12 was neutral on stall-dominated agg1; expected positive here).
__global__ __launch_bounds__(256) void k_out(
    const int* __restrict__ row_off, const int* __restrict__ srcs,
    const unsigned short* __restrict__ h2, const float* __restrict__ ndst,
    const void* __restrict__ b2, const int* __restrict__ mode,
    void* __restrict__ out)
{
    const bool f32 = (mode[0] != 0);
    const int lane = threadIdx.x & 63;
    const int q  = lane >> 3;
    const int li = lane & 7;
    const float b2v0 = ldf(b2, 2*li,   f32);
    const float b2v1 = ldf(b2, 2*li+1, f32);

    const int wid = (blockIdx.x * blockDim.x + threadIdx.x) >> 6;
    const int nw  = (gridDim.x * blockDim.x) >> 6;
    const unsigned* __restrict__ h2v = (const unsigned*)h2;
    const unsigned uli = (unsigned)li;

    int row = wid;
    if (row >= NN) return;
    int beg = row_off[row];
    int end = row_off[row + 1];
    float nd = ndst[row];

    while (row < NN) {
        const int nrow = row + nw;
        int nbeg = 0, nend = 0;
        float nnd = 0.f;
        if (nrow < NN) {
            nbeg = row_off[nrow];
            nend = row_off[nrow + 1];
            nnd  = ndst[nrow];
        }

        float a0 = 0.f, a1 = 0.f, c0 = 0.f, c1 = 0.f;
        const int e1 = end - 1;
        int i = beg + q;
        while (i < end) {
            const int j1 = i + 8, j2 = i + 16, j3 = i + 24;
            const int t1 = (j1 < end) ? j1 : e1;
            const int t2 = (j2 < end) ? j2 : e1;
            const int t3 = (j3 < end) ? j3 : e1;
            const int s0 = srcs[(unsigned)i];
            const int s1 = srcs[(unsigned)t1];
            const int s2 = srcs[(unsigned)t2];
            const int s3 = srcs[(unsigned)t3];
            const unsigned u0 = h2v[(unsigned)s0 * 8u + uli];
            const unsigned u1 = h2v[(unsigned)s1 * 8u + uli];
            const unsigned u2 = h2v[(unsigned)s2 * 8u + uli];
            const unsigned u3 = h2v[(unsigned)s3 * 8u + uli];
            a0 += bflo(u0); a1 += bfhi(u0);
            if (j1 < end) { c0 += bflo(u1); c1 += bfhi(u1); }
            if (j2 < end) { a0 += bflo(u2); a1 += bfhi(u2); }
            if (j3 < end) { c0 += bflo(u3); c1 += bfhi(u3); }
            i += 32;
        }
        a0 += c0; a1 += c1;
        #pragma unroll
        for (int off = 8; off <= 32; off <<= 1) {
            a0 += __shfl_xor(a0, off);
            a1 += __shfl_xor(a1, off);
        }
        float v0 = fmaf(a0, nd, b2v0);
        float v1 = fmaf(a1, nd, b2v1);
        float m = fmaxf(v0, v1);
        #pragma unroll
        for (int off = 1; off <= 4; off <<= 1) m = fmaxf(m, __shfl_xor(m, off));
        float sm = __expf(v0 - m) + __expf(v1 - m);
        #pragma unroll
        for (int off = 1; off <= 4; off <<= 1) sm += __shfl_xor(sm, off);
        const float lsm = __logf(sm);
        const float r0 = v0 - m - lsm, r1 = v1 - m - lsm;
        if (q == 0) {
            if (f32) {
                float2 o; o.x = r0; o.y = r1;
                *(float2*)((float*)out + (size_t)row * NC + 2*li) = o;
            } else {
                unsigned o = ((unsigned)f2us_rn(r1) << 16) | (unsigned)f2us_rn(r0);
                *(unsigned*)((unsigned short*)out + (size_t)row * NC + 2*li) = o;
            }
        }

        row = nrow; beg = nbeg; end = nend; nd = nnd;
    }
}

extern "C" void kernel_launch(void* const* d_in, const int* in_sizes, int n_in,
                              void* d_out, int out_size, void* d_ws, size_t ws_size,
                              hipStream_t stream) {
    const void* x  = d_in[0];
    const int* src = (const int*)d_in[1];
    const int* dst = (const int*)d_in[2];
    const void* W1 = d_in[3];
    const void* b1 = d_in[4];
    const void* W2 = d_in[5];
    const void* b2 = d_in[6];

    // ---- workspace layout (R1-identical) ----
    char* ws = (char*)d_ws;
    const size_t O_MODE = 0;                     // 1 KB
    const size_t O_W1F  = 1024;                  // fragment-ordered W1 (bf16), 16384 B
    const size_t O_CNT  = O_W1F + 16384;         // counts_d + counts_s = 401408
    const size_t O_CS   = O_CNT  + 401408;       // csum 2048 + coff 2048
    const size_t O_DEG  = O_CS   + 4096;         // 800000 (fallback only)
    const size_t O_NSRC = O_DEG  + 800000;
    const size_t O_NDST = O_NSRC + 400000;
    const size_t O_ROW  = O_NDST + 400000;       // (NN+1)*4 padded
    const size_t O_CUR  = O_ROW  + 400128;       // fallback per-node cursors
    const size_t O_BS   = O_CUR  + 400128;       // bsum 2048 + boff 2048 (fallback)
    const size_t O_SRCS = O_BS   + 4096;         // NE*4
    const size_t O_H2   = O_SRCS + 6400000;      // NN*NC*2 bf16
    const size_t O_H1   = O_H2   + 3200000;      // NN*NH*2 bf16 = 12800000
    // packed (NE*4) + packed2 (NE*2) alias into h1 (dead before gemm1)
    const size_t NEED = O_H1 + 12800000;         // ~25.2 MB
    const bool fast_csr = ws_size >= NEED;

    int*   mode     = (int*)(ws + O_MODE);
    unsigned short* W1f = (unsigned short*)(ws + O_W1F);
    int*   counts_d = (int*)(ws + O_CNT);
    int*   counts_s = counts_d + BBUK * GBIN;
    int*   csum     = (int*)(ws + O_CS);
    int*   coff     = (int*)(ws + O_CS + 2048);
    int*   deg_out  = (int*)(ws + O_DEG);
    int*   deg_in   = deg_out + NN;
    float* nsrc     = (float*)(ws + O_NSRC);
    float* ndst     = (float*)(ws + O_NDST);
    int*   row_off  = (int*)(ws + O_ROW);
    int*   cursor   = (int*)(ws + O_CUR);
    int*   bsum     = (int*)(ws + O_BS);
    int*   boff     = (int*)(ws + O_BS + 2048);
    int*   srcs_s   = (int*)(ws + O_SRCS);
    unsigned short* h2 = (unsigned short*)(ws + O_H2);
    unsigned short* h1 = (unsigned short*)(ws + O_H1);
    unsigned int*   packed  = (unsigned int*)(ws + O_H1);
    unsigned short* packed2 = (unsigned short*)(ws + O_H1 + 6400000);

    if (fast_csr) {
        k_hist2s<<<GBIN + 1, 1024, 0, stream>>>(src, dst, counts_d, counts_s,
                                                (const unsigned short*)x, W1, W1f, mode);
        k_cs_a<<<2 * NCB, 256, 0, stream>>>(counts_d, csum);
        k_cs_c<<<2 * NCB, 256, 0, stream>>>(counts_d, csum);
        k_binscatter2<<<GBIN, 1024, 0, stream>>>(src, dst, counts_d, counts_s, packed, packed2);
        k_bucket2<<<BBUK, 1024, 0, stream>>>(counts_d, counts_s, packed, packed2,
                                             row_off, ndst, nsrc, srcs_s);
    } else {
        k_sniffprep<<<1, 256, 0, stream>>>((const unsigned short*)x, W1, W1f, mode);
        hipMemsetAsync(deg_out, 0, 2 * (size_t)NN * sizeof(int), stream);
        k_deg<<<(NE / 4 + 255) / 256, 256, 0, stream>>>((const int4*)src, (const int4*)dst, deg_out, deg_in);
        k_scan_a<<<NB1, 256, 0, stream>>>(deg_in, bsum);
        k_scan_b<<<1, 512, 0, stream>>>(bsum, boff);
        k_scan_c<<<NB1, 256, 0, stream>>>(deg_in, deg_out, boff, row_off, cursor, nsrc, ndst);
        k_scatter<<<(NE + 255) / 256, 256, 0, stream>>>(src, dst, cursor, srcs_s);
    }
    k_gemm1_mfma<<<NGRP, 256, 0, stream>>>(x, W1f, nsrc, h1, mode);
    k_agg1csr<<<2048, 256, 0, stream>>>(row_off, srcs_s, h1, ndst, nsrc, b1, W2, mode, h2);
    k_out<<<2048, 256, 0, stream>>>(row_off, srcs_s, h2, ndst, b2, mode, d_out);
}